// Round 13
// baseline (1227.465 us; speedup 1.0000x reference)
//
#include <hip/hip_runtime.h>
#include <hip/hip_bf16.h>
#include <math.h>

// RQ-VAE pipeline. Index path = numpy-fp32 bit-exact (validated r3-r12).
// Round 13: encoder GEMM "gemm_sb" — B fetched via wave-uniform SCALAR loads
// (s_load -> SGPR, v_fmac with SGPR operand), LDS carries only A (8 B/lane/k).
// Removes the LDS-pipe bottleneck (was 96 B/lane/k vs ~85 B/cyc capability).
// Per-(row,col) chain stays sequential-K single-acc fmaf -> bit-exact.
// vq9 / gemm_z / MFMA decoder / prep = r12.

#define N_ROWS 131072
#define D_IN   384
#define H_DIM  256
#define L_DIM  32
#define K_CB   512
#define Q_ST   4
#define VQ_RPB 128                 // rows per VQ block
#define NPART  (N_ROWS / VQ_RPB)   // 1024 commit partials

typedef __attribute__((ext_vector_type(8))) short short8v;
typedef __attribute__((ext_vector_type(4))) float f32x4;

__device__ __forceinline__ ushort f2bf(float v)
{
    __hip_bfloat16 b = __float2bfloat16(v);
    return *reinterpret_cast<ushort*>(&b);
}

// np.sum(v*v) for n=32: numpy pairwise 8-accumulator order, products pre-rounded.
__device__ __forceinline__ float np_sumsq32(const float* __restrict__ v)
{
    #pragma clang fp contract(off)
    float s0 = v[0]*v[0], s1 = v[1]*v[1], s2 = v[2]*v[2], s3 = v[3]*v[3];
    float s4 = v[4]*v[4], s5 = v[5]*v[5], s6 = v[6]*v[6], s7 = v[7]*v[7];
    s0 = s0 + v[8]*v[8];   s1 = s1 + v[9]*v[9];   s2 = s2 + v[10]*v[10]; s3 = s3 + v[11]*v[11];
    s4 = s4 + v[12]*v[12]; s5 = s5 + v[13]*v[13]; s6 = s6 + v[14]*v[14]; s7 = s7 + v[15]*v[15];
    s0 = s0 + v[16]*v[16]; s1 = s1 + v[17]*v[17]; s2 = s2 + v[18]*v[18]; s3 = s3 + v[19]*v[19];
    s4 = s4 + v[20]*v[20]; s5 = s5 + v[21]*v[21]; s6 = s6 + v[22]*v[22]; s7 = s7 + v[23]*v[23];
    s0 = s0 + v[24]*v[24]; s1 = s1 + v[25]*v[25]; s2 = s2 + v[26]*v[26]; s3 = s3 + v[27]*v[27];
    s4 = s4 + v[28]*v[28]; s5 = s5 + v[29]*v[29]; s6 = s6 + v[30]*v[30]; s7 = s7 + v[31]*v[31];
    return ((s0 + s1) + (s2 + s3)) + ((s4 + s5) + (s6 + s7));
}

// ---------------- fp32 GEMM, scalar-B path (encoder; bit-exact) -------------------
// 128 rows x 256 cols per block, 256 thr = 4 waves. Wave w owns cols
// [64w, 64w+64) -> B row segment is wave-uniform -> s_load into SGPRs; FMAs
// read b from SGPR (no LDS/VMEM cost). Lane owns rows l and l+64; A staged in
// LDS [k][row] (pad 133), 2x ds_read_b32 per k. Sequential-K single-acc fmaf.
template<bool RELU>
__global__ __launch_bounds__(256)
void gemm_sb(const float* __restrict__ A, const float* __restrict__ B,
             const float* __restrict__ bias, float* __restrict__ C,
             int K)
{
    #pragma clang fp contract(off)
    __shared__ float As2[32][133];   // [k][row]
    const int t = threadIdx.x;
    const int l = t & 63;
    const int w = __builtin_amdgcn_readfirstlane(t >> 6);   // wave id (SGPR)
    const int cbase = w << 6;
    const size_t row0 = (size_t)blockIdx.x * 128;

    float acc0[64], acc1[64];
    #pragma unroll
    for (int j = 0; j < 64; ++j) { acc0[j] = 0.f; acc1[j] = 0.f; }

    const int ar = t >> 3, ak = (t & 7) << 2;   // A staging coords

    for (int k0 = 0; k0 < K; k0 += 32) {
        #pragma unroll
        for (int i = 0; i < 4; ++i) {
            int r = ar + (i << 5);
            float4 v = *reinterpret_cast<const float4*>(A + (row0 + r) * (size_t)K + k0 + ak);
            As2[ak + 0][r] = v.x; As2[ak + 1][r] = v.y;
            As2[ak + 2][r] = v.z; As2[ak + 3][r] = v.w;
        }
        __syncthreads();
        #pragma unroll 2
        for (int k = 0; k < 32; ++k) {
            float a0 = As2[k][l];
            float a1 = As2[k][l + 64];
            const float* __restrict__ Brow = B + (size_t)(k0 + k) * H_DIM + cbase;
            #pragma unroll
            for (int j = 0; j < 64; ++j) {
                float bv = Brow[j];                    // uniform -> s_load
                acc0[j] = fmaf(a0, bv, acc0[j]);
                acc1[j] = fmaf(a1, bv, acc1[j]);
            }
        }
        __syncthreads();
    }

    // epilogue: bias + relu, float4 stores (per-thread contiguous 256B rows)
    float* C0 = C + (row0 + l) * (size_t)H_DIM + cbase;
    float* C1 = C + (row0 + l + 64) * (size_t)H_DIM + cbase;
    #pragma unroll
    for (int g = 0; g < 16; ++g) {
        float v0[4], v1[4];
        #pragma unroll
        for (int j = 0; j < 4; ++j) {
            float bv = bias[cbase + (g << 2) + j];
            float u0 = acc0[(g << 2) + j] + bv;
            float u1 = acc1[(g << 2) + j] + bv;
            if (RELU) { u0 = fmaxf(u0, 0.0f); u1 = fmaxf(u1, 0.0f); }
            v0[j] = u0; v1[j] = u1;
        }
        *reinterpret_cast<float4*>(C0 + (g << 2)) = *reinterpret_cast<float4*>(&v0[0]);
        *reinterpret_cast<float4*>(C1 + (g << 2)) = *reinterpret_cast<float4*>(&v1[0]);
    }
}

// ---------------- z-GEMM: Z[M,32] = A[M,256] @ W[256,32] + b (bit-exact) ----------
__global__ __launch_bounds__(256)
void gemm_z(const float* __restrict__ A, const float* __restrict__ W,
            const float* __restrict__ bv, float* __restrict__ Z)
{
    #pragma clang fp contract(off)
    __shared__ float As2[32][133];
    __shared__ float Ws[32][36];
    const int t = threadIdx.x;
    const int cgz = t & 7, rgz = t >> 3;
    const size_t row0 = (size_t)blockIdx.x * 128;

    float acc[4][4];
    #pragma unroll
    for (int i = 0; i < 4; ++i)
        #pragma unroll
        for (int j = 0; j < 4; ++j) acc[i][j] = 0.f;

    const int ar = t >> 3, ak = (t & 7) << 2;
    for (int k0 = 0; k0 < H_DIM; k0 += 32) {
        #pragma unroll
        for (int i = 0; i < 4; ++i) {
            int r = ar + (i << 5);
            float4 v = *reinterpret_cast<const float4*>(A + (row0 + r) * (size_t)H_DIM + k0 + ak);
            As2[ak + 0][r] = v.x; As2[ak + 1][r] = v.y;
            As2[ak + 2][r] = v.z; As2[ak + 3][r] = v.w;
        }
        {
            int kr = t >> 3, cc = (t & 7) << 2;
            float4 v = *reinterpret_cast<const float4*>(W + (size_t)(k0 + kr) * L_DIM + cc);
            *reinterpret_cast<float4*>(&Ws[kr][cc]) = v;
        }
        __syncthreads();
        #pragma unroll
        for (int k = 0; k < 32; ++k) {
            float a[4], w[4];
            *reinterpret_cast<float4*>(&a[0]) = *reinterpret_cast<const float4*>(&As2[k][rgz << 2]);
            *reinterpret_cast<float4*>(&w[0]) = *reinterpret_cast<const float4*>(&Ws[k][cgz << 2]);
            #pragma unroll
            for (int i = 0; i < 4; ++i)
                #pragma unroll
                for (int j = 0; j < 4; ++j) acc[i][j] = fmaf(a[i], w[j], acc[i][j]);
        }
        __syncthreads();
    }
    #pragma unroll
    for (int i = 0; i < 4; ++i) {
        size_t row = row0 + (rgz << 2) + i;
        float v[4];
        #pragma unroll
        for (int j = 0; j < 4; ++j) v[j] = acc[i][j] + bv[(cgz << 2) + j];
        *reinterpret_cast<float4*>(Z + row * L_DIM + (cgz << 2)) = *reinterpret_cast<float4*>(&v[0]);
    }
}

// ---------------- cnorm (numpy order) ---------------------------------------------
__global__ __launch_bounds__(256)
void cnorm_kernel(const float* __restrict__ cbs, float* __restrict__ cnorm)
{
    #pragma clang fp contract(off)
    int g = blockIdx.x * 256 + threadIdx.x;
    const float* c = cbs + (size_t)g * L_DIM;
    float cl[L_DIM];
    #pragma unroll
    for (int l = 0; l < L_DIM; ++l) cl[l] = c[l];
    cnorm[g] = np_sumsq32(cl);
}

// ---------------- dec-weight prep: fp32 [K][N] -> bf16 transposed [N][K] ----------
__global__ __launch_bounds__(256)
void prep_wt(const float* __restrict__ W, ushort* __restrict__ Wt, int K, int N)
{
    int g = blockIdx.x * 256 + threadIdx.x;
    if (g >= K * N) return;
    int n = g / K, k = g - n * K;
    Wt[g] = f2bf(W[(size_t)k * N + n]);
}

// ---------------- residual VQ v9 (r11): dual-row + 4-wave col-split ---------------
__global__ __launch_bounds__(256)
void vq9_kernel(const float* __restrict__ zbuf, const float* __restrict__ cbs,
                const float* __restrict__ cnorm_g, ushort* __restrict__ zqb,
                float* __restrict__ idxOut, double* __restrict__ commitPart,
                int rowBase)
{
    #pragma clang fp contract(off)
    __shared__ float  cbL[K_CB * L_DIM];   // 64 KB
    __shared__ float  cnL[K_CB];           // 2 KB
    __shared__ float  sd0[4][64], sd1[4][64];
    __shared__ int    si0[4][64], si1[4][64];
    __shared__ double sred[256];

    const int t = threadIdx.x;
    const int w = t >> 6;
    const int l = t & 63;
    const size_t lrow0 = (size_t)blockIdx.x * VQ_RPB + l;
    const size_t lrow1 = lrow0 + 64;
    const size_t grow0 = (size_t)rowBase + lrow0;
    const size_t grow1 = (size_t)rowBase + lrow1;
    const int c0 = w << 7;

    float r0[L_DIM], r1[L_DIM];
    {
        const float4* zp0 = reinterpret_cast<const float4*>(zbuf + lrow0 * L_DIM);
        const float4* zp1 = reinterpret_cast<const float4*>(zbuf + lrow1 * L_DIM);
        #pragma unroll
        for (int j = 0; j < 8; ++j) {
            float4 a = zp0[j], b = zp1[j];
            r0[4*j+0]=a.x; r0[4*j+1]=a.y; r0[4*j+2]=a.z; r0[4*j+3]=a.w;
            r1[4*j+0]=b.x; r1[4*j+1]=b.y; r1[4*j+2]=b.z; r1[4*j+3]=b.w;
        }
    }

    int bidx0[Q_ST], bidx1[Q_ST];
    double cAcc = 0.0;

    #pragma unroll 1
    for (int q = 0; q < Q_ST; ++q) {
        __syncthreads();
        {
            const float4* src = reinterpret_cast<const float4*>(cbs + (size_t)q * K_CB * L_DIM);
            float4* dst = reinterpret_cast<float4*>(cbL);
            #pragma unroll
            for (int i = 0; i < 16; ++i) dst[t + (i << 8)] = src[t + (i << 8)];
            cnL[t]       = cnorm_g[q * K_CB + t];
            cnL[t + 256] = cnorm_g[q * K_CB + t + 256];
        }
        __syncthreads();

        float rr0 = np_sumsq32(r0);
        float rr1 = np_sumsq32(r1);
        float bd0 = __builtin_inff(), bd1 = __builtin_inff();
        int   bi0 = c0, bi1 = c0;

        #pragma unroll 1
        for (int cc = 0; cc < 128; cc += 2) {
            const int c = c0 + cc;
            const float4* w0 = reinterpret_cast<const float4*>(cbL + (c << 5));
            const float4* w1 = w0 + 8;
            float a00 = 0.f, a01 = 0.f, a10 = 0.f, a11 = 0.f;
            #pragma unroll
            for (int j = 0; j < 8; ++j) {
                float4 u = w0[j], v = w1[j];
                a00 = fmaf(r0[4*j+0], u.x, a00);  a01 = fmaf(r0[4*j+0], v.x, a01);
                a10 = fmaf(r1[4*j+0], u.x, a10);  a11 = fmaf(r1[4*j+0], v.x, a11);
                a00 = fmaf(r0[4*j+1], u.y, a00);  a01 = fmaf(r0[4*j+1], v.y, a01);
                a10 = fmaf(r1[4*j+1], u.y, a10);  a11 = fmaf(r1[4*j+1], v.y, a11);
                a00 = fmaf(r0[4*j+2], u.z, a00);  a01 = fmaf(r0[4*j+2], v.z, a01);
                a10 = fmaf(r1[4*j+2], u.z, a10);  a11 = fmaf(r1[4*j+2], v.z, a11);
                a00 = fmaf(r0[4*j+3], u.w, a00);  a01 = fmaf(r0[4*j+3], v.w, a01);
                a10 = fmaf(r1[4*j+3], u.w, a10);  a11 = fmaf(r1[4*j+3], v.w, a11);
            }
            float cn0 = cnL[c], cn1 = cnL[c + 1];
            float d00 = (rr0 - 2.0f * a00) + cn0;
            float d01 = (rr0 - 2.0f * a01) + cn1;
            float d10 = (rr1 - 2.0f * a10) + cn0;
            float d11 = (rr1 - 2.0f * a11) + cn1;
            if (d00 < bd0) { bd0 = d00; bi0 = c; }
            if (d01 < bd0) { bd0 = d01; bi0 = c + 1; }
            if (d10 < bd1) { bd1 = d10; bi1 = c; }
            if (d11 < bd1) { bd1 = d11; bi1 = c + 1; }
        }

        sd0[w][l] = bd0; si0[w][l] = bi0;
        sd1[w][l] = bd1; si1[w][l] = bi1;
        __syncthreads();

        float g0 = sd0[0][l]; int gi0 = si0[0][l];
        float g1 = sd1[0][l]; int gi1 = si1[0][l];
        #pragma unroll
        for (int ww = 1; ww < 4; ++ww) {
            float od = sd0[ww][l]; int oi = si0[ww][l];
            if (od < g0 || (od == g0 && oi < gi0)) { g0 = od; gi0 = oi; }
            od = sd1[ww][l]; oi = si1[ww][l];
            if (od < g1 || (od == g1 && oi < gi1)) { g1 = od; gi1 = oi; }
        }
        bidx0[q] = gi0;
        bidx1[q] = gi1;

        {
            const float4* p0 = reinterpret_cast<const float4*>(cbL + (gi0 << 5));
            const float4* p1 = reinterpret_cast<const float4*>(cbL + (gi1 << 5));
            float cs0 = 0.f, cs1 = 0.f;
            #pragma unroll
            for (int j = 0; j < 8; ++j) {
                float4 v0 = p0[j], v1 = p1[j];
                float df;
                df = v0.x - r0[4*j+0]; cs0 = fmaf(df, df, cs0); r0[4*j+0] = r0[4*j+0] - v0.x;
                df = v0.y - r0[4*j+1]; cs0 = fmaf(df, df, cs0); r0[4*j+1] = r0[4*j+1] - v0.y;
                df = v0.z - r0[4*j+2]; cs0 = fmaf(df, df, cs0); r0[4*j+2] = r0[4*j+2] - v0.z;
                df = v0.w - r0[4*j+3]; cs0 = fmaf(df, df, cs0); r0[4*j+3] = r0[4*j+3] - v0.w;
                df = v1.x - r1[4*j+0]; cs1 = fmaf(df, df, cs1); r1[4*j+0] = r1[4*j+0] - v1.x;
                df = v1.y - r1[4*j+1]; cs1 = fmaf(df, df, cs1); r1[4*j+1] = r1[4*j+1] - v1.y;
                df = v1.z - r1[4*j+2]; cs1 = fmaf(df, df, cs1); r1[4*j+2] = r1[4*j+2] - v1.z;
                df = v1.w - r1[4*j+3]; cs1 = fmaf(df, df, cs1); r1[4*j+3] = r1[4*j+3] - v1.w;
            }
            if (w == 0) { cAcc += (double)cs0; cAcc += (double)cs1; }
        }
    }

    if (w == 0) {
        float4 iv0 = make_float4((float)bidx0[0], (float)bidx0[1], (float)bidx0[2], (float)bidx0[3]);
        float4 iv1 = make_float4((float)bidx1[0], (float)bidx1[1], (float)bidx1[2], (float)bidx1[3]);
        *reinterpret_cast<float4*>(idxOut + grow0 * Q_ST) = iv0;
        *reinterpret_cast<float4*>(idxOut + grow1 * Q_ST) = iv1;

        const float4* zp0 = reinterpret_cast<const float4*>(zbuf + lrow0 * L_DIM);
        const float4* zp1 = reinterpret_cast<const float4*>(zbuf + lrow1 * L_DIM);
        ushort zq0[L_DIM], zq1[L_DIM];
        #pragma unroll
        for (int j = 0; j < 8; ++j) {
            float4 a = zp0[j], b = zp1[j];
            zq0[4*j+0] = f2bf(a.x - r0[4*j+0]);
            zq0[4*j+1] = f2bf(a.y - r0[4*j+1]);
            zq0[4*j+2] = f2bf(a.z - r0[4*j+2]);
            zq0[4*j+3] = f2bf(a.w - r0[4*j+3]);
            zq1[4*j+0] = f2bf(b.x - r1[4*j+0]);
            zq1[4*j+1] = f2bf(b.y - r1[4*j+1]);
            zq1[4*j+2] = f2bf(b.z - r1[4*j+2]);
            zq1[4*j+3] = f2bf(b.w - r1[4*j+3]);
        }
        uint4* o0 = reinterpret_cast<uint4*>(zqb + lrow0 * L_DIM);
        uint4* o1 = reinterpret_cast<uint4*>(zqb + lrow1 * L_DIM);
        const uint4* s0 = reinterpret_cast<const uint4*>(zq0);
        const uint4* s1 = reinterpret_cast<const uint4*>(zq1);
        #pragma unroll
        for (int j = 0; j < 4; ++j) { o0[j] = s0[j]; o1[j] = s1[j]; }
    }

    sred[t] = (w == 0) ? cAcc : 0.0;
    __syncthreads();
    for (int s = 128; s > 0; s >>= 1) {
        if (t < s) sred[t] += sred[t + s];
        __syncthreads();
    }
    if (t == 0) commitPart[rowBase / VQ_RPB + blockIdx.x] = sred[0];
}

// ---------------- bf16 MFMA GEMM (decoder; r6 version) ----------------------------
template<bool RELU, bool OUTBF16>
__global__ __launch_bounds__(256)
void mfma_gemm(const ushort* __restrict__ A, const ushort* __restrict__ Bt,
               const float* __restrict__ bias, void* __restrict__ Cout,
               int K, int Nout)
{
    __shared__ ushort As[128][40];
    __shared__ ushort Bs[128][40];
    const int t    = threadIdx.x;
    const int lane = t & 63;
    const int wid  = t >> 6;
    const int wr = wid >> 1, wc = wid & 1;
    const size_t row0 = (size_t)blockIdx.x * 128;
    const int    col0 = blockIdx.y * 128;

    f32x4 acc[4][4] = {};
    const int srow = t >> 1;
    const int sh   = (t & 1) << 4;

    for (int k0 = 0; k0 < K; k0 += 32) {
        {
            const ushort* ap = A + (row0 + srow) * (size_t)K + k0 + sh;
            uint4 v0 = *reinterpret_cast<const uint4*>(ap);
            uint4 v1 = *reinterpret_cast<const uint4*>(ap + 8);
            *reinterpret_cast<uint4*>(&As[srow][sh])     = v0;
            *reinterpret_cast<uint4*>(&As[srow][sh + 8]) = v1;
            const ushort* bp = Bt + (size_t)(col0 + srow) * K + k0 + sh;
            uint4 w0 = *reinterpret_cast<const uint4*>(bp);
            uint4 w1 = *reinterpret_cast<const uint4*>(bp + 8);
            *reinterpret_cast<uint4*>(&Bs[srow][sh])     = w0;
            *reinterpret_cast<uint4*>(&Bs[srow][sh + 8]) = w1;
        }
        __syncthreads();
        const int l15 = lane & 15, lk = (lane >> 4) << 3;
        short8v af[4], bf[4];
        #pragma unroll
        for (int f = 0; f < 4; ++f) {
            af[f] = *reinterpret_cast<const short8v*>(&As[(wr << 6) + (f << 4) + l15][lk]);
            bf[f] = *reinterpret_cast<const short8v*>(&Bs[(wc << 6) + (f << 4) + l15][lk]);
        }
        #pragma unroll
        for (int i = 0; i < 4; ++i)
            #pragma unroll
            for (int j = 0; j < 4; ++j)
                acc[i][j] = __builtin_amdgcn_mfma_f32_16x16x32_bf16(af[i], bf[j], acc[i][j], 0, 0, 0);
        __syncthreads();
    }

    const int l15 = lane & 15, lr4 = (lane >> 4) << 2;
    #pragma unroll
    for (int i = 0; i < 4; ++i) {
        #pragma unroll
        for (int j = 0; j < 4; ++j) {
            int col = col0 + (wc << 6) + (j << 4) + l15;
            float bv = bias[col];
            #pragma unroll
            for (int rj = 0; rj < 4; ++rj) {
                size_t row = row0 + (wr << 6) + (i << 4) + lr4 + rj;
                float v = acc[i][j][rj] + bv;
                if (RELU) v = fmaxf(v, 0.f);
                if (OUTBF16)
                    reinterpret_cast<ushort*>(Cout)[row * Nout + col] = f2bf(v);
                else
                    reinterpret_cast<float*>(Cout)[row * Nout + col] = v;
            }
        }
    }
}

// ---------------- final commit reduction (1024 partials) --------------------------
__global__ __launch_bounds__(256)
void commit_finalize(const double* __restrict__ commitPart, float* __restrict__ outCommit)
{
    __shared__ double sred[256];
    const int t = threadIdx.x;
    double s = 0.0;
    for (int i = t; i < NPART; i += 256) s += commitPart[i];
    sred[t] = s;
    __syncthreads();
    for (int st = 128; st > 0; st >>= 1) {
        if (t < st) sred[t] += sred[t + st];
        __syncthreads();
    }
    if (t == 0)
        outCommit[0] = (float)(sred[0] / ((double)N_ROWS * (double)L_DIM));
}

extern "C" void kernel_launch(void* const* d_in, const int* in_sizes, int n_in,
                              void* d_out, int out_size, void* d_ws, size_t ws_size,
                              hipStream_t stream)
{
    const float* x      = (const float*)d_in[0];
    const float* enc_w1 = (const float*)d_in[1];
    const float* enc_b1 = (const float*)d_in[2];
    const float* enc_w2 = (const float*)d_in[3];
    const float* enc_b2 = (const float*)d_in[4];
    const float* enc_w3 = (const float*)d_in[5];
    const float* enc_b3 = (const float*)d_in[6];
    const float* dec_w1 = (const float*)d_in[7];
    const float* dec_b1 = (const float*)d_in[8];
    const float* dec_w2 = (const float*)d_in[9];
    const float* dec_b2 = (const float*)d_in[10];
    const float* dec_w3 = (const float*)d_in[11];
    const float* dec_b3 = (const float*)d_in[12];
    const float* cbs    = (const float*)d_in[13];

    float* out       = (float*)d_out;
    float* xrec      = out;
    float* idxOut    = out + (size_t)N_ROWS * D_IN;
    float* commitOut = idxOut + (size_t)N_ROWS * Q_ST;

    // ws layout:
    //   cnorm  f32[2048]     @0      (8192)
    //   commit f64[1024]     @8192   (8192)
    //   w1t    u16[256*32]   @16384  (16384)
    //   w2t    u16[256*256]  @32768  (131072)
    //   w3t    u16[384*256]  @163840 (196608)
    //   bufs                 @360448
    char*   wsb        = (char*)d_ws;
    float*  cnorm      = (float*)wsb;
    double* commitPart = (double*)(wsb + 8192);
    ushort* w1t        = (ushort*)(wsb + 16384);
    ushort* w2t        = (ushort*)(wsb + 32768);
    ushort* w3t        = (ushort*)(wsb + 163840);
    char*   bufs       = wsb + 360448;

    // per-row bytes: zbuf 128 + bufA 1024 + bufB 1024 + zqb 64 + h1b 512 + h2b 512 = 3264
    size_t availB = (ws_size > 360448) ? ws_size - 360448 : 0;
    long long chunk = (long long)(availB / 3264);
    chunk = (chunk / 256) * 256;
    if (chunk > N_ROWS) chunk = N_ROWS;
    if (chunk < 256) chunk = 256;

    float*  zbuf = (float*)bufs;
    float*  bufA = zbuf + (size_t)chunk * L_DIM;
    float*  bufB = bufA + (size_t)chunk * H_DIM;
    ushort* zqb  = (ushort*)(bufB + (size_t)chunk * H_DIM);
    ushort* h1b  = zqb + (size_t)chunk * L_DIM;
    ushort* h2b  = h1b + (size_t)chunk * H_DIM;

    cnorm_kernel<<<8, 256, 0, stream>>>(cbs, cnorm);
    prep_wt<<<(L_DIM  * H_DIM + 255) / 256, 256, 0, stream>>>(dec_w1, w1t, L_DIM, H_DIM);
    prep_wt<<<(H_DIM * H_DIM + 255) / 256, 256, 0, stream>>>(dec_w2, w2t, H_DIM, H_DIM);
    prep_wt<<<(H_DIM * D_IN + 255) / 256, 256, 0, stream>>>(dec_w3, w3t, H_DIM, D_IN);

    for (long long ro = 0; ro < N_ROWS; ro += chunk) {
        long long R = N_ROWS - ro;
        if (R > chunk) R = chunk;
        unsigned g1 = (unsigned)(R / 128);
        dim3 g2(g1, 2);
        dim3 g3(g1, 3);
        // encoder (bit-exact fp32; scalar-B GEMM)
        gemm_sb<true><<<g1, 256, 0, stream>>>(x + ro * D_IN, enc_w1, enc_b1, bufA, D_IN);
        gemm_sb<true><<<g1, 256, 0, stream>>>(bufA, enc_w2, enc_b2, bufB, H_DIM);
        gemm_z<<<g1, 256, 0, stream>>>(bufB, enc_w3, enc_b3, zbuf);
        // residual VQ (bit-exact; writes bf16 z_q)
        vq9_kernel<<<(unsigned)(R / VQ_RPB), 256, 0, stream>>>(zbuf, cbs, cnorm, zqb,
                                                               idxOut, commitPart, (int)ro);
        // decoder (bf16 MFMA)
        mfma_gemm<true,  true ><<<g2, 256, 0, stream>>>(zqb, w1t, dec_b1, h1b, L_DIM, H_DIM);
        mfma_gemm<true,  true ><<<g2, 256, 0, stream>>>(h1b, w2t, dec_b2, h2b, H_DIM, H_DIM);
        mfma_gemm<false, false><<<g3, 256, 0, stream>>>(h2b, w3t, dec_b3, xrec + ro * D_IN, H_DIM, D_IN);
    }

    commit_finalize<<<1, 256, 0, stream>>>(commitPart, commitOut);
}

// Round 14
// 1227.153 us; speedup vs baseline: 1.0003x; 1.0003x over previous
//
#include <hip/hip_runtime.h>
#include <hip/hip_bf16.h>
#include <math.h>

// RQ-VAE pipeline. Index path = numpy-fp32 bit-exact (validated r3-r12).
// Round 14: r13's scalar-B encoder GEMM with the spill fixed —
// __launch_bounds__(256,1) gives the allocator ~256 VGPR/wave so the 128
// per-thread accumulators live in registers (r13: VGPR capped at 80 -> 577MB
// scratch spill traffic, VALUBusy 37%). Arithmetic unchanged -> bit-exact.
// vq9 / gemm_z / MFMA decoder / prep = r12.

#define N_ROWS 131072
#define D_IN   384
#define H_DIM  256
#define L_DIM  32
#define K_CB   512
#define Q_ST   4
#define VQ_RPB 128                 // rows per VQ block
#define NPART  (N_ROWS / VQ_RPB)   // 1024 commit partials

typedef __attribute__((ext_vector_type(8))) short short8v;
typedef __attribute__((ext_vector_type(4))) float f32x4;

__device__ __forceinline__ ushort f2bf(float v)
{
    __hip_bfloat16 b = __float2bfloat16(v);
    return *reinterpret_cast<ushort*>(&b);
}

// np.sum(v*v) for n=32: numpy pairwise 8-accumulator order, products pre-rounded.
__device__ __forceinline__ float np_sumsq32(const float* __restrict__ v)
{
    #pragma clang fp contract(off)
    float s0 = v[0]*v[0], s1 = v[1]*v[1], s2 = v[2]*v[2], s3 = v[3]*v[3];
    float s4 = v[4]*v[4], s5 = v[5]*v[5], s6 = v[6]*v[6], s7 = v[7]*v[7];
    s0 = s0 + v[8]*v[8];   s1 = s1 + v[9]*v[9];   s2 = s2 + v[10]*v[10]; s3 = s3 + v[11]*v[11];
    s4 = s4 + v[12]*v[12]; s5 = s5 + v[13]*v[13]; s6 = s6 + v[14]*v[14]; s7 = s7 + v[15]*v[15];
    s0 = s0 + v[16]*v[16]; s1 = s1 + v[17]*v[17]; s2 = s2 + v[18]*v[18]; s3 = s3 + v[19]*v[19];
    s4 = s4 + v[20]*v[20]; s5 = s5 + v[21]*v[21]; s6 = s6 + v[22]*v[22]; s7 = s7 + v[23]*v[23];
    s0 = s0 + v[24]*v[24]; s1 = s1 + v[25]*v[25]; s2 = s2 + v[26]*v[26]; s3 = s3 + v[27]*v[27];
    s4 = s4 + v[28]*v[28]; s5 = s5 + v[29]*v[29]; s6 = s6 + v[30]*v[30]; s7 = s7 + v[31]*v[31];
    return ((s0 + s1) + (s2 + s3)) + ((s4 + s5) + (s6 + s7));
}

// ---------------- fp32 GEMM, scalar-B path (encoder; bit-exact) -------------------
// 128 rows x 256 cols per block, 256 thr = 4 waves. Wave w owns cols
// [64w, 64w+64) -> B row segment is wave-uniform -> s_load into SGPRs; FMAs
// read b from SGPR. Lane owns rows l and l+64; A staged in LDS [k][row]
// (pad 133), 2x ds_read_b32 per k. Sequential-K single-acc fmaf.
// launch_bounds(256,1): 128 accumulators MUST stay in VGPRs (r13 spilled).
template<bool RELU>
__global__ __launch_bounds__(256, 1)
void gemm_sb(const float* __restrict__ A, const float* __restrict__ B,
             const float* __restrict__ bias, float* __restrict__ C,
             int K)
{
    #pragma clang fp contract(off)
    __shared__ float As2[32][133];   // [k][row]
    const int t = threadIdx.x;
    const int l = t & 63;
    const int w = __builtin_amdgcn_readfirstlane(t >> 6);   // wave id (SGPR)
    const int cbase = w << 6;
    const size_t row0 = (size_t)blockIdx.x * 128;

    float acc0[64], acc1[64];
    #pragma unroll
    for (int j = 0; j < 64; ++j) { acc0[j] = 0.f; acc1[j] = 0.f; }

    const int ar = t >> 3, ak = (t & 7) << 2;   // A staging coords

    for (int k0 = 0; k0 < K; k0 += 32) {
        #pragma unroll
        for (int i = 0; i < 4; ++i) {
            int r = ar + (i << 5);
            float4 v = *reinterpret_cast<const float4*>(A + (row0 + r) * (size_t)K + k0 + ak);
            As2[ak + 0][r] = v.x; As2[ak + 1][r] = v.y;
            As2[ak + 2][r] = v.z; As2[ak + 3][r] = v.w;
        }
        __syncthreads();
        #pragma unroll 2
        for (int k = 0; k < 32; ++k) {
            float a0 = As2[k][l];
            float a1 = As2[k][l + 64];
            const float* __restrict__ Brow = B + (size_t)(k0 + k) * H_DIM + cbase;
            #pragma unroll
            for (int j = 0; j < 64; ++j) {
                float bv = Brow[j];                    // uniform -> s_load
                acc0[j] = fmaf(a0, bv, acc0[j]);
                acc1[j] = fmaf(a1, bv, acc1[j]);
            }
        }
        __syncthreads();
    }

    // epilogue: bias + relu, float4 stores (per-thread contiguous rows)
    float* C0 = C + (row0 + l) * (size_t)H_DIM + cbase;
    float* C1 = C + (row0 + l + 64) * (size_t)H_DIM + cbase;
    #pragma unroll
    for (int g = 0; g < 16; ++g) {
        float v0[4], v1[4];
        #pragma unroll
        for (int j = 0; j < 4; ++j) {
            float bv = bias[cbase + (g << 2) + j];
            float u0 = acc0[(g << 2) + j] + bv;
            float u1 = acc1[(g << 2) + j] + bv;
            if (RELU) { u0 = fmaxf(u0, 0.0f); u1 = fmaxf(u1, 0.0f); }
            v0[j] = u0; v1[j] = u1;
        }
        *reinterpret_cast<float4*>(C0 + (g << 2)) = *reinterpret_cast<float4*>(&v0[0]);
        *reinterpret_cast<float4*>(C1 + (g << 2)) = *reinterpret_cast<float4*>(&v1[0]);
    }
}

// ---------------- z-GEMM: Z[M,32] = A[M,256] @ W[256,32] + b (bit-exact) ----------
__global__ __launch_bounds__(256)
void gemm_z(const float* __restrict__ A, const float* __restrict__ W,
            const float* __restrict__ bv, float* __restrict__ Z)
{
    #pragma clang fp contract(off)
    __shared__ float As2[32][133];
    __shared__ float Ws[32][36];
    const int t = threadIdx.x;
    const int cgz = t & 7, rgz = t >> 3;
    const size_t row0 = (size_t)blockIdx.x * 128;

    float acc[4][4];
    #pragma unroll
    for (int i = 0; i < 4; ++i)
        #pragma unroll
        for (int j = 0; j < 4; ++j) acc[i][j] = 0.f;

    const int ar = t >> 3, ak = (t & 7) << 2;
    for (int k0 = 0; k0 < H_DIM; k0 += 32) {
        #pragma unroll
        for (int i = 0; i < 4; ++i) {
            int r = ar + (i << 5);
            float4 v = *reinterpret_cast<const float4*>(A + (row0 + r) * (size_t)H_DIM + k0 + ak);
            As2[ak + 0][r] = v.x; As2[ak + 1][r] = v.y;
            As2[ak + 2][r] = v.z; As2[ak + 3][r] = v.w;
        }
        {
            int kr = t >> 3, cc = (t & 7) << 2;
            float4 v = *reinterpret_cast<const float4*>(W + (size_t)(k0 + kr) * L_DIM + cc);
            *reinterpret_cast<float4*>(&Ws[kr][cc]) = v;
        }
        __syncthreads();
        #pragma unroll
        for (int k = 0; k < 32; ++k) {
            float a[4], w[4];
            *reinterpret_cast<float4*>(&a[0]) = *reinterpret_cast<const float4*>(&As2[k][rgz << 2]);
            *reinterpret_cast<float4*>(&w[0]) = *reinterpret_cast<const float4*>(&Ws[k][cgz << 2]);
            #pragma unroll
            for (int i = 0; i < 4; ++i)
                #pragma unroll
                for (int j = 0; j < 4; ++j) acc[i][j] = fmaf(a[i], w[j], acc[i][j]);
        }
        __syncthreads();
    }
    #pragma unroll
    for (int i = 0; i < 4; ++i) {
        size_t row = row0 + (rgz << 2) + i;
        float v[4];
        #pragma unroll
        for (int j = 0; j < 4; ++j) v[j] = acc[i][j] + bv[(cgz << 2) + j];
        *reinterpret_cast<float4*>(Z + row * L_DIM + (cgz << 2)) = *reinterpret_cast<float4*>(&v[0]);
    }
}

// ---------------- cnorm (numpy order) ---------------------------------------------
__global__ __launch_bounds__(256)
void cnorm_kernel(const float* __restrict__ cbs, float* __restrict__ cnorm)
{
    #pragma clang fp contract(off)
    int g = blockIdx.x * 256 + threadIdx.x;
    const float* c = cbs + (size_t)g * L_DIM;
    float cl[L_DIM];
    #pragma unroll
    for (int l = 0; l < L_DIM; ++l) cl[l] = c[l];
    cnorm[g] = np_sumsq32(cl);
}

// ---------------- dec-weight prep: fp32 [K][N] -> bf16 transposed [N][K] ----------
__global__ __launch_bounds__(256)
void prep_wt(const float* __restrict__ W, ushort* __restrict__ Wt, int K, int N)
{
    int g = blockIdx.x * 256 + threadIdx.x;
    if (g >= K * N) return;
    int n = g / K, k = g - n * K;
    Wt[g] = f2bf(W[(size_t)k * N + n]);
}

// ---------------- residual VQ v9 (r11): dual-row + 4-wave col-split ---------------
__global__ __launch_bounds__(256)
void vq9_kernel(const float* __restrict__ zbuf, const float* __restrict__ cbs,
                const float* __restrict__ cnorm_g, ushort* __restrict__ zqb,
                float* __restrict__ idxOut, double* __restrict__ commitPart,
                int rowBase)
{
    #pragma clang fp contract(off)
    __shared__ float  cbL[K_CB * L_DIM];   // 64 KB
    __shared__ float  cnL[K_CB];           // 2 KB
    __shared__ float  sd0[4][64], sd1[4][64];
    __shared__ int    si0[4][64], si1[4][64];
    __shared__ double sred[256];

    const int t = threadIdx.x;
    const int w = t >> 6;
    const int l = t & 63;
    const size_t lrow0 = (size_t)blockIdx.x * VQ_RPB + l;
    const size_t lrow1 = lrow0 + 64;
    const size_t grow0 = (size_t)rowBase + lrow0;
    const size_t grow1 = (size_t)rowBase + lrow1;
    const int c0 = w << 7;

    float r0[L_DIM], r1[L_DIM];
    {
        const float4* zp0 = reinterpret_cast<const float4*>(zbuf + lrow0 * L_DIM);
        const float4* zp1 = reinterpret_cast<const float4*>(zbuf + lrow1 * L_DIM);
        #pragma unroll
        for (int j = 0; j < 8; ++j) {
            float4 a = zp0[j], b = zp1[j];
            r0[4*j+0]=a.x; r0[4*j+1]=a.y; r0[4*j+2]=a.z; r0[4*j+3]=a.w;
            r1[4*j+0]=b.x; r1[4*j+1]=b.y; r1[4*j+2]=b.z; r1[4*j+3]=b.w;
        }
    }

    int bidx0[Q_ST], bidx1[Q_ST];
    double cAcc = 0.0;

    #pragma unroll 1
    for (int q = 0; q < Q_ST; ++q) {
        __syncthreads();
        {
            const float4* src = reinterpret_cast<const float4*>(cbs + (size_t)q * K_CB * L_DIM);
            float4* dst = reinterpret_cast<float4*>(cbL);
            #pragma unroll
            for (int i = 0; i < 16; ++i) dst[t + (i << 8)] = src[t + (i << 8)];
            cnL[t]       = cnorm_g[q * K_CB + t];
            cnL[t + 256] = cnorm_g[q * K_CB + t + 256];
        }
        __syncthreads();

        float rr0 = np_sumsq32(r0);
        float rr1 = np_sumsq32(r1);
        float bd0 = __builtin_inff(), bd1 = __builtin_inff();
        int   bi0 = c0, bi1 = c0;

        #pragma unroll 1
        for (int cc = 0; cc < 128; cc += 2) {
            const int c = c0 + cc;
            const float4* w0 = reinterpret_cast<const float4*>(cbL + (c << 5));
            const float4* w1 = w0 + 8;
            float a00 = 0.f, a01 = 0.f, a10 = 0.f, a11 = 0.f;
            #pragma unroll
            for (int j = 0; j < 8; ++j) {
                float4 u = w0[j], v = w1[j];
                a00 = fmaf(r0[4*j+0], u.x, a00);  a01 = fmaf(r0[4*j+0], v.x, a01);
                a10 = fmaf(r1[4*j+0], u.x, a10);  a11 = fmaf(r1[4*j+0], v.x, a11);
                a00 = fmaf(r0[4*j+1], u.y, a00);  a01 = fmaf(r0[4*j+1], v.y, a01);
                a10 = fmaf(r1[4*j+1], u.y, a10);  a11 = fmaf(r1[4*j+1], v.y, a11);
                a00 = fmaf(r0[4*j+2], u.z, a00);  a01 = fmaf(r0[4*j+2], v.z, a01);
                a10 = fmaf(r1[4*j+2], u.z, a10);  a11 = fmaf(r1[4*j+2], v.z, a11);
                a00 = fmaf(r0[4*j+3], u.w, a00);  a01 = fmaf(r0[4*j+3], v.w, a01);
                a10 = fmaf(r1[4*j+3], u.w, a10);  a11 = fmaf(r1[4*j+3], v.w, a11);
            }
            float cn0 = cnL[c], cn1 = cnL[c + 1];
            float d00 = (rr0 - 2.0f * a00) + cn0;
            float d01 = (rr0 - 2.0f * a01) + cn1;
            float d10 = (rr1 - 2.0f * a10) + cn0;
            float d11 = (rr1 - 2.0f * a11) + cn1;
            if (d00 < bd0) { bd0 = d00; bi0 = c; }
            if (d01 < bd0) { bd0 = d01; bi0 = c + 1; }
            if (d10 < bd1) { bd1 = d10; bi1 = c; }
            if (d11 < bd1) { bd1 = d11; bi1 = c + 1; }
        }

        sd0[w][l] = bd0; si0[w][l] = bi0;
        sd1[w][l] = bd1; si1[w][l] = bi1;
        __syncthreads();

        float g0 = sd0[0][l]; int gi0 = si0[0][l];
        float g1 = sd1[0][l]; int gi1 = si1[0][l];
        #pragma unroll
        for (int ww = 1; ww < 4; ++ww) {
            float od = sd0[ww][l]; int oi = si0[ww][l];
            if (od < g0 || (od == g0 && oi < gi0)) { g0 = od; gi0 = oi; }
            od = sd1[ww][l]; oi = si1[ww][l];
            if (od < g1 || (od == g1 && oi < gi1)) { g1 = od; gi1 = oi; }
        }
        bidx0[q] = gi0;
        bidx1[q] = gi1;

        {
            const float4* p0 = reinterpret_cast<const float4*>(cbL + (gi0 << 5));
            const float4* p1 = reinterpret_cast<const float4*>(cbL + (gi1 << 5));
            float cs0 = 0.f, cs1 = 0.f;
            #pragma unroll
            for (int j = 0; j < 8; ++j) {
                float4 v0 = p0[j], v1 = p1[j];
                float df;
                df = v0.x - r0[4*j+0]; cs0 = fmaf(df, df, cs0); r0[4*j+0] = r0[4*j+0] - v0.x;
                df = v0.y - r0[4*j+1]; cs0 = fmaf(df, df, cs0); r0[4*j+1] = r0[4*j+1] - v0.y;
                df = v0.z - r0[4*j+2]; cs0 = fmaf(df, df, cs0); r0[4*j+2] = r0[4*j+2] - v0.z;
                df = v0.w - r0[4*j+3]; cs0 = fmaf(df, df, cs0); r0[4*j+3] = r0[4*j+3] - v0.w;
                df = v1.x - r1[4*j+0]; cs1 = fmaf(df, df, cs1); r1[4*j+0] = r1[4*j+0] - v1.x;
                df = v1.y - r1[4*j+1]; cs1 = fmaf(df, df, cs1); r1[4*j+1] = r1[4*j+1] - v1.y;
                df = v1.z - r1[4*j+2]; cs1 = fmaf(df, df, cs1); r1[4*j+2] = r1[4*j+2] - v1.z;
                df = v1.w - r1[4*j+3]; cs1 = fmaf(df, df, cs1); r1[4*j+3] = r1[4*j+3] - v1.w;
            }
            if (w == 0) { cAcc += (double)cs0; cAcc += (double)cs1; }
        }
    }

    if (w == 0) {
        float4 iv0 = make_float4((float)bidx0[0], (float)bidx0[1], (float)bidx0[2], (float)bidx0[3]);
        float4 iv1 = make_float4((float)bidx1[0], (float)bidx1[1], (float)bidx1[2], (float)bidx1[3]);
        *reinterpret_cast<float4*>(idxOut + grow0 * Q_ST) = iv0;
        *reinterpret_cast<float4*>(idxOut + grow1 * Q_ST) = iv1;

        const float4* zp0 = reinterpret_cast<const float4*>(zbuf + lrow0 * L_DIM);
        const float4* zp1 = reinterpret_cast<const float4*>(zbuf + lrow1 * L_DIM);
        ushort zq0[L_DIM], zq1[L_DIM];
        #pragma unroll
        for (int j = 0; j < 8; ++j) {
            float4 a = zp0[j], b = zp1[j];
            zq0[4*j+0] = f2bf(a.x - r0[4*j+0]);
            zq0[4*j+1] = f2bf(a.y - r0[4*j+1]);
            zq0[4*j+2] = f2bf(a.z - r0[4*j+2]);
            zq0[4*j+3] = f2bf(a.w - r0[4*j+3]);
            zq1[4*j+0] = f2bf(b.x - r1[4*j+0]);
            zq1[4*j+1] = f2bf(b.y - r1[4*j+1]);
            zq1[4*j+2] = f2bf(b.z - r1[4*j+2]);
            zq1[4*j+3] = f2bf(b.w - r1[4*j+3]);
        }
        uint4* o0 = reinterpret_cast<uint4*>(zqb + lrow0 * L_DIM);
        uint4* o1 = reinterpret_cast<uint4*>(zqb + lrow1 * L_DIM);
        const uint4* s0 = reinterpret_cast<const uint4*>(zq0);
        const uint4* s1 = reinterpret_cast<const uint4*>(zq1);
        #pragma unroll
        for (int j = 0; j < 4; ++j) { o0[j] = s0[j]; o1[j] = s1[j]; }
    }

    sred[t] = (w == 0) ? cAcc : 0.0;
    __syncthreads();
    for (int s = 128; s > 0; s >>= 1) {
        if (t < s) sred[t] += sred[t + s];
        __syncthreads();
    }
    if (t == 0) commitPart[rowBase / VQ_RPB + blockIdx.x] = sred[0];
}

// ---------------- bf16 MFMA GEMM (decoder; r6 version) ----------------------------
template<bool RELU, bool OUTBF16>
__global__ __launch_bounds__(256)
void mfma_gemm(const ushort* __restrict__ A, const ushort* __restrict__ Bt,
               const float* __restrict__ bias, void* __restrict__ Cout,
               int K, int Nout)
{
    __shared__ ushort As[128][40];
    __shared__ ushort Bs[128][40];
    const int t    = threadIdx.x;
    const int lane = t & 63;
    const int wid  = t >> 6;
    const int wr = wid >> 1, wc = wid & 1;
    const size_t row0 = (size_t)blockIdx.x * 128;
    const int    col0 = blockIdx.y * 128;

    f32x4 acc[4][4] = {};
    const int srow = t >> 1;
    const int sh   = (t & 1) << 4;

    for (int k0 = 0; k0 < K; k0 += 32) {
        {
            const ushort* ap = A + (row0 + srow) * (size_t)K + k0 + sh;
            uint4 v0 = *reinterpret_cast<const uint4*>(ap);
            uint4 v1 = *reinterpret_cast<const uint4*>(ap + 8);
            *reinterpret_cast<uint4*>(&As[srow][sh])     = v0;
            *reinterpret_cast<uint4*>(&As[srow][sh + 8]) = v1;
            const ushort* bp = Bt + (size_t)(col0 + srow) * K + k0 + sh;
            uint4 w0 = *reinterpret_cast<const uint4*>(bp);
            uint4 w1 = *reinterpret_cast<const uint4*>(bp + 8);
            *reinterpret_cast<uint4*>(&Bs[srow][sh])     = w0;
            *reinterpret_cast<uint4*>(&Bs[srow][sh + 8]) = w1;
        }
        __syncthreads();
        const int l15 = lane & 15, lk = (lane >> 4) << 3;
        short8v af[4], bf[4];
        #pragma unroll
        for (int f = 0; f < 4; ++f) {
            af[f] = *reinterpret_cast<const short8v*>(&As[(wr << 6) + (f << 4) + l15][lk]);
            bf[f] = *reinterpret_cast<const short8v*>(&Bs[(wc << 6) + (f << 4) + l15][lk]);
        }
        #pragma unroll
        for (int i = 0; i < 4; ++i)
            #pragma unroll
            for (int j = 0; j < 4; ++j)
                acc[i][j] = __builtin_amdgcn_mfma_f32_16x16x32_bf16(af[i], bf[j], acc[i][j], 0, 0, 0);
        __syncthreads();
    }

    const int l15 = lane & 15, lr4 = (lane >> 4) << 2;
    #pragma unroll
    for (int i = 0; i < 4; ++i) {
        #pragma unroll
        for (int j = 0; j < 4; ++j) {
            int col = col0 + (wc << 6) + (j << 4) + l15;
            float bv = bias[col];
            #pragma unroll
            for (int rj = 0; rj < 4; ++rj) {
                size_t row = row0 + (wr << 6) + (i << 4) + lr4 + rj;
                float v = acc[i][j][rj] + bv;
                if (RELU) v = fmaxf(v, 0.f);
                if (OUTBF16)
                    reinterpret_cast<ushort*>(Cout)[row * Nout + col] = f2bf(v);
                else
                    reinterpret_cast<float*>(Cout)[row * Nout + col] = v;
            }
        }
    }
}

// ---------------- final commit reduction (1024 partials) --------------------------
__global__ __launch_bounds__(256)
void commit_finalize(const double* __restrict__ commitPart, float* __restrict__ outCommit)
{
    __shared__ double sred[256];
    const int t = threadIdx.x;
    double s = 0.0;
    for (int i = t; i < NPART; i += 256) s += commitPart[i];
    sred[t] = s;
    __syncthreads();
    for (int st = 128; st > 0; st >>= 1) {
        if (t < st) sred[t] += sred[t + st];
        __syncthreads();
    }
    if (t == 0)
        outCommit[0] = (float)(sred[0] / ((double)N_ROWS * (double)L_DIM));
}

extern "C" void kernel_launch(void* const* d_in, const int* in_sizes, int n_in,
                              void* d_out, int out_size, void* d_ws, size_t ws_size,
                              hipStream_t stream)
{
    const float* x      = (const float*)d_in[0];
    const float* enc_w1 = (const float*)d_in[1];
    const float* enc_b1 = (const float*)d_in[2];
    const float* enc_w2 = (const float*)d_in[3];
    const float* enc_b2 = (const float*)d_in[4];
    const float* enc_w3 = (const float*)d_in[5];
    const float* enc_b3 = (const float*)d_in[6];
    const float* dec_w1 = (const float*)d_in[7];
    const float* dec_b1 = (const float*)d_in[8];
    const float* dec_w2 = (const float*)d_in[9];
    const float* dec_b2 = (const float*)d_in[10];
    const float* dec_w3 = (const float*)d_in[11];
    const float* dec_b3 = (const float*)d_in[12];
    const float* cbs    = (const float*)d_in[13];

    float* out       = (float*)d_out;
    float* xrec      = out;
    float* idxOut    = out + (size_t)N_ROWS * D_IN;
    float* commitOut = idxOut + (size_t)N_ROWS * Q_ST;

    // ws layout:
    //   cnorm  f32[2048]     @0      (8192)
    //   commit f64[1024]     @8192   (8192)
    //   w1t    u16[256*32]   @16384  (16384)
    //   w2t    u16[256*256]  @32768  (131072)
    //   w3t    u16[384*256]  @163840 (196608)
    //   bufs                 @360448
    char*   wsb        = (char*)d_ws;
    float*  cnorm      = (float*)wsb;
    double* commitPart = (double*)(wsb + 8192);
    ushort* w1t        = (ushort*)(wsb + 16384);
    ushort* w2t        = (ushort*)(wsb + 32768);
    ushort* w3t        = (ushort*)(wsb + 163840);
    char*   bufs       = wsb + 360448;

    // per-row bytes: zbuf 128 + bufA 1024 + bufB 1024 + zqb 64 + h1b 512 + h2b 512 = 3264
    size_t availB = (ws_size > 360448) ? ws_size - 360448 : 0;
    long long chunk = (long long)(availB / 3264);
    chunk = (chunk / 256) * 256;
    if (chunk > N_ROWS) chunk = N_ROWS;
    if (chunk < 256) chunk = 256;

    float*  zbuf = (float*)bufs;
    float*  bufA = zbuf + (size_t)chunk * L_DIM;
    float*  bufB = bufA + (size_t)chunk * H_DIM;
    ushort* zqb  = (ushort*)(bufB + (size_t)chunk * H_DIM);
    ushort* h1b  = zqb + (size_t)chunk * L_DIM;
    ushort* h2b  = h1b + (size_t)chunk * H_DIM;

    cnorm_kernel<<<8, 256, 0, stream>>>(cbs, cnorm);
    prep_wt<<<(L_DIM  * H_DIM + 255) / 256, 256, 0, stream>>>(dec_w1, w1t, L_DIM, H_DIM);
    prep_wt<<<(H_DIM * H_DIM + 255) / 256, 256, 0, stream>>>(dec_w2, w2t, H_DIM, H_DIM);
    prep_wt<<<(H_DIM * D_IN + 255) / 256, 256, 0, stream>>>(dec_w3, w3t, H_DIM, D_IN);

    for (long long ro = 0; ro < N_ROWS; ro += chunk) {
        long long R = N_ROWS - ro;
        if (R > chunk) R = chunk;
        unsigned g1 = (unsigned)(R / 128);
        dim3 g2(g1, 2);
        dim3 g3(g1, 3);
        // encoder (bit-exact fp32; scalar-B GEMM, no-spill)
        gemm_sb<true><<<g1, 256, 0, stream>>>(x + ro * D_IN, enc_w1, enc_b1, bufA, D_IN);
        gemm_sb<true><<<g1, 256, 0, stream>>>(bufA, enc_w2, enc_b2, bufB, H_DIM);
        gemm_z<<<g1, 256, 0, stream>>>(bufB, enc_w3, enc_b3, zbuf);
        // residual VQ (bit-exact; writes bf16 z_q)
        vq9_kernel<<<(unsigned)(R / VQ_RPB), 256, 0, stream>>>(zbuf, cbs, cnorm, zqb,
                                                               idxOut, commitPart, (int)ro);
        // decoder (bf16 MFMA)
        mfma_gemm<true,  true ><<<g2, 256, 0, stream>>>(zqb, w1t, dec_b1, h1b, L_DIM, H_DIM);
        mfma_gemm<true,  true ><<<g2, 256, 0, stream>>>(h1b, w2t, dec_b2, h2b, H_DIM, H_DIM);
        mfma_gemm<false, false><<<g3, 256, 0, stream>>>(h2b, w3t, dec_b3, xrec + ro * D_IN, H_DIM, D_IN);
    }

    commit_finalize<<<1, 256, 0, stream>>>(commitPart, commitOut);
}

// Round 15
// 922.536 us; speedup vs baseline: 1.3305x; 1.3302x over previous
//
#include <hip/hip_runtime.h>
#include <hip/hip_bf16.h>
#include <math.h>

// RQ-VAE pipeline. Index path = numpy-fp32 bit-exact (validated r3-r12).
// Round 15: revert to r12 (best, 919us); ONE change: encoder GEMM BK 32->16.
// r12's 49KB LDS rounded to a 64KB granule -> 2 blocks/CU; staging barriers
// stalled both resident blocks (VALUBusy 56%). BK=16 => ~25KB LDS -> 4
// blocks/CU, cross-block overlap of staging stalls. Same sequential-K
// single-acc fmaf chains -> bit-exact. vq9 / gemm_z / decoder / prep = r12.

#define N_ROWS 131072
#define D_IN   384
#define H_DIM  256
#define L_DIM  32
#define K_CB   512
#define Q_ST   4
#define VQ_RPB 128                 // rows per VQ block
#define NPART  (N_ROWS / VQ_RPB)   // 1024 commit partials

typedef __attribute__((ext_vector_type(8))) short short8v;
typedef __attribute__((ext_vector_type(4))) float f32x4;

__device__ __forceinline__ ushort f2bf(float v)
{
    __hip_bfloat16 b = __float2bfloat16(v);
    return *reinterpret_cast<ushort*>(&b);
}

// np.sum(v*v) for n=32: numpy pairwise 8-accumulator order, products pre-rounded.
__device__ __forceinline__ float np_sumsq32(const float* __restrict__ v)
{
    #pragma clang fp contract(off)
    float s0 = v[0]*v[0], s1 = v[1]*v[1], s2 = v[2]*v[2], s3 = v[3]*v[3];
    float s4 = v[4]*v[4], s5 = v[5]*v[5], s6 = v[6]*v[6], s7 = v[7]*v[7];
    s0 = s0 + v[8]*v[8];   s1 = s1 + v[9]*v[9];   s2 = s2 + v[10]*v[10]; s3 = s3 + v[11]*v[11];
    s4 = s4 + v[12]*v[12]; s5 = s5 + v[13]*v[13]; s6 = s6 + v[14]*v[14]; s7 = s7 + v[15]*v[15];
    s0 = s0 + v[16]*v[16]; s1 = s1 + v[17]*v[17]; s2 = s2 + v[18]*v[18]; s3 = s3 + v[19]*v[19];
    s4 = s4 + v[20]*v[20]; s5 = s5 + v[21]*v[21]; s6 = s6 + v[22]*v[22]; s7 = s7 + v[23]*v[23];
    s0 = s0 + v[24]*v[24]; s1 = s1 + v[25]*v[25]; s2 = s2 + v[26]*v[26]; s3 = s3 + v[27]*v[27];
    s4 = s4 + v[28]*v[28]; s5 = s5 + v[29]*v[29]; s6 = s6 + v[30]*v[30]; s7 = s7 + v[31]*v[31];
    return ((s0 + s1) + (s2 + s3)) + ((s4 + s5) + (s6 + s7));
}

// ---------------- fp32 tiled GEMM (encoder; bit-exact path; BK=16) ----------------
// 128 rows x 256 cols per block, BK=16, 256 threads, 8x16/thread.
// LDS ~25KB -> 4 blocks/CU resident. Sequential-K single-acc fmaf
// (bit-exact numpy sgemm, K<=384 single KC panel).
template<bool RELU>
__global__ __launch_bounds__(256, 2)
void gemm_bias(const float* __restrict__ A, const float* __restrict__ B,
               const float* __restrict__ bias, float* __restrict__ C,
               int K)
{
    #pragma clang fp contract(off)
    __shared__ float As2[16][133];   // [k][row], pad 133
    __shared__ float Bs[16][256];    // [k][col]
    const int t  = threadIdx.x;
    const int tc = t & 15;
    const int tr = t >> 4;
    const size_t row0 = (size_t)blockIdx.x * 128;

    float acc[8][16];
    #pragma unroll
    for (int i = 0; i < 8; ++i)
        #pragma unroll
        for (int j = 0; j < 16; ++j) acc[i][j] = 0.f;

    const int ar = t >> 2, ak = (t & 3) << 2;   // A staging: 2 float4 / thread
    const int brow = t >> 6, bcol = (t & 63) << 2;  // B staging: 4 float4 / thread

    for (int k0 = 0; k0 < K; k0 += 16) {
        #pragma unroll
        for (int i = 0; i < 2; ++i) {
            int r = ar + (i << 6);
            float4 v = *reinterpret_cast<const float4*>(A + (row0 + r) * (size_t)K + k0 + ak);
            As2[ak + 0][r] = v.x; As2[ak + 1][r] = v.y;
            As2[ak + 2][r] = v.z; As2[ak + 3][r] = v.w;
        }
        #pragma unroll
        for (int i = 0; i < 4; ++i) {
            int rb = brow + (i << 2);
            float4 v = *reinterpret_cast<const float4*>(B + (size_t)(k0 + rb) * H_DIM + bcol);
            *reinterpret_cast<float4*>(&Bs[rb][bcol]) = v;
        }
        __syncthreads();
        #pragma unroll
        for (int k = 0; k < 16; ++k) {
            float a[8], b[16];
            *reinterpret_cast<float4*>(&a[0]) = *reinterpret_cast<const float4*>(&As2[k][tr << 3]);
            *reinterpret_cast<float4*>(&a[4]) = *reinterpret_cast<const float4*>(&As2[k][(tr << 3) + 4]);
            #pragma unroll
            for (int g = 0; g < 4; ++g)
                *reinterpret_cast<float4*>(&b[g << 2]) =
                    *reinterpret_cast<const float4*>(&Bs[k][(g << 6) + (tc << 2)]);
            #pragma unroll
            for (int i = 0; i < 8; ++i)
                #pragma unroll
                for (int j = 0; j < 16; ++j) acc[i][j] = fmaf(a[i], b[j], acc[i][j]);
        }
        __syncthreads();
    }

    #pragma unroll
    for (int i = 0; i < 8; ++i) {
        size_t r = row0 + (tr << 3) + i;
        #pragma unroll
        for (int g = 0; g < 4; ++g) {
            int c = (g << 6) + (tc << 2);
            float v[4];
            #pragma unroll
            for (int j = 0; j < 4; ++j) {
                float u = acc[i][(g << 2) + j] + bias[c + j];
                if (RELU) u = fmaxf(u, 0.0f);
                v[j] = u;
            }
            *reinterpret_cast<float4*>(C + r * H_DIM + c) = *reinterpret_cast<float4*>(&v[0]);
        }
    }
}

// ---------------- z-GEMM: Z[M,32] = A[M,256] @ W[256,32] + b (bit-exact) ----------
__global__ __launch_bounds__(256)
void gemm_z(const float* __restrict__ A, const float* __restrict__ W,
            const float* __restrict__ bv, float* __restrict__ Z)
{
    #pragma clang fp contract(off)
    __shared__ float As2[32][133];
    __shared__ float Ws[32][36];
    const int t = threadIdx.x;
    const int cgz = t & 7, rgz = t >> 3;
    const size_t row0 = (size_t)blockIdx.x * 128;

    float acc[4][4];
    #pragma unroll
    for (int i = 0; i < 4; ++i)
        #pragma unroll
        for (int j = 0; j < 4; ++j) acc[i][j] = 0.f;

    const int ar = t >> 3, ak = (t & 7) << 2;
    for (int k0 = 0; k0 < H_DIM; k0 += 32) {
        #pragma unroll
        for (int i = 0; i < 4; ++i) {
            int r = ar + (i << 5);
            float4 v = *reinterpret_cast<const float4*>(A + (row0 + r) * (size_t)H_DIM + k0 + ak);
            As2[ak + 0][r] = v.x; As2[ak + 1][r] = v.y;
            As2[ak + 2][r] = v.z; As2[ak + 3][r] = v.w;
        }
        {
            int kr = t >> 3, cc = (t & 7) << 2;
            float4 v = *reinterpret_cast<const float4*>(W + (size_t)(k0 + kr) * L_DIM + cc);
            *reinterpret_cast<float4*>(&Ws[kr][cc]) = v;
        }
        __syncthreads();
        #pragma unroll
        for (int k = 0; k < 32; ++k) {
            float a[4], w[4];
            *reinterpret_cast<float4*>(&a[0]) = *reinterpret_cast<const float4*>(&As2[k][rgz << 2]);
            *reinterpret_cast<float4*>(&w[0]) = *reinterpret_cast<const float4*>(&Ws[k][cgz << 2]);
            #pragma unroll
            for (int i = 0; i < 4; ++i)
                #pragma unroll
                for (int j = 0; j < 4; ++j) acc[i][j] = fmaf(a[i], w[j], acc[i][j]);
        }
        __syncthreads();
    }
    #pragma unroll
    for (int i = 0; i < 4; ++i) {
        size_t row = row0 + (rgz << 2) + i;
        float v[4];
        #pragma unroll
        for (int j = 0; j < 4; ++j) v[j] = acc[i][j] + bv[(cgz << 2) + j];
        *reinterpret_cast<float4*>(Z + row * L_DIM + (cgz << 2)) = *reinterpret_cast<float4*>(&v[0]);
    }
}

// ---------------- cnorm (numpy order) ---------------------------------------------
__global__ __launch_bounds__(256)
void cnorm_kernel(const float* __restrict__ cbs, float* __restrict__ cnorm)
{
    #pragma clang fp contract(off)
    int g = blockIdx.x * 256 + threadIdx.x;
    const float* c = cbs + (size_t)g * L_DIM;
    float cl[L_DIM];
    #pragma unroll
    for (int l = 0; l < L_DIM; ++l) cl[l] = c[l];
    cnorm[g] = np_sumsq32(cl);
}

// ---------------- dec-weight prep: fp32 [K][N] -> bf16 transposed [N][K] ----------
__global__ __launch_bounds__(256)
void prep_wt(const float* __restrict__ W, ushort* __restrict__ Wt, int K, int N)
{
    int g = blockIdx.x * 256 + threadIdx.x;
    if (g >= K * N) return;
    int n = g / K, k = g - n * K;
    Wt[g] = f2bf(W[(size_t)k * N + n]);
}

// ---------------- residual VQ v9 (r11): dual-row + 4-wave col-split ---------------
__global__ __launch_bounds__(256)
void vq9_kernel(const float* __restrict__ zbuf, const float* __restrict__ cbs,
                const float* __restrict__ cnorm_g, ushort* __restrict__ zqb,
                float* __restrict__ idxOut, double* __restrict__ commitPart,
                int rowBase)
{
    #pragma clang fp contract(off)
    __shared__ float  cbL[K_CB * L_DIM];   // 64 KB
    __shared__ float  cnL[K_CB];           // 2 KB
    __shared__ float  sd0[4][64], sd1[4][64];
    __shared__ int    si0[4][64], si1[4][64];
    __shared__ double sred[256];

    const int t = threadIdx.x;
    const int w = t >> 6;
    const int l = t & 63;
    const size_t lrow0 = (size_t)blockIdx.x * VQ_RPB + l;
    const size_t lrow1 = lrow0 + 64;
    const size_t grow0 = (size_t)rowBase + lrow0;
    const size_t grow1 = (size_t)rowBase + lrow1;
    const int c0 = w << 7;

    float r0[L_DIM], r1[L_DIM];
    {
        const float4* zp0 = reinterpret_cast<const float4*>(zbuf + lrow0 * L_DIM);
        const float4* zp1 = reinterpret_cast<const float4*>(zbuf + lrow1 * L_DIM);
        #pragma unroll
        for (int j = 0; j < 8; ++j) {
            float4 a = zp0[j], b = zp1[j];
            r0[4*j+0]=a.x; r0[4*j+1]=a.y; r0[4*j+2]=a.z; r0[4*j+3]=a.w;
            r1[4*j+0]=b.x; r1[4*j+1]=b.y; r1[4*j+2]=b.z; r1[4*j+3]=b.w;
        }
    }

    int bidx0[Q_ST], bidx1[Q_ST];
    double cAcc = 0.0;

    #pragma unroll 1
    for (int q = 0; q < Q_ST; ++q) {
        __syncthreads();
        {
            const float4* src = reinterpret_cast<const float4*>(cbs + (size_t)q * K_CB * L_DIM);
            float4* dst = reinterpret_cast<float4*>(cbL);
            #pragma unroll
            for (int i = 0; i < 16; ++i) dst[t + (i << 8)] = src[t + (i << 8)];
            cnL[t]       = cnorm_g[q * K_CB + t];
            cnL[t + 256] = cnorm_g[q * K_CB + t + 256];
        }
        __syncthreads();

        float rr0 = np_sumsq32(r0);
        float rr1 = np_sumsq32(r1);
        float bd0 = __builtin_inff(), bd1 = __builtin_inff();
        int   bi0 = c0, bi1 = c0;

        #pragma unroll 1
        for (int cc = 0; cc < 128; cc += 2) {
            const int c = c0 + cc;
            const float4* w0 = reinterpret_cast<const float4*>(cbL + (c << 5));
            const float4* w1 = w0 + 8;
            float a00 = 0.f, a01 = 0.f, a10 = 0.f, a11 = 0.f;
            #pragma unroll
            for (int j = 0; j < 8; ++j) {
                float4 u = w0[j], v = w1[j];
                a00 = fmaf(r0[4*j+0], u.x, a00);  a01 = fmaf(r0[4*j+0], v.x, a01);
                a10 = fmaf(r1[4*j+0], u.x, a10);  a11 = fmaf(r1[4*j+0], v.x, a11);
                a00 = fmaf(r0[4*j+1], u.y, a00);  a01 = fmaf(r0[4*j+1], v.y, a01);
                a10 = fmaf(r1[4*j+1], u.y, a10);  a11 = fmaf(r1[4*j+1], v.y, a11);
                a00 = fmaf(r0[4*j+2], u.z, a00);  a01 = fmaf(r0[4*j+2], v.z, a01);
                a10 = fmaf(r1[4*j+2], u.z, a10);  a11 = fmaf(r1[4*j+2], v.z, a11);
                a00 = fmaf(r0[4*j+3], u.w, a00);  a01 = fmaf(r0[4*j+3], v.w, a01);
                a10 = fmaf(r1[4*j+3], u.w, a10);  a11 = fmaf(r1[4*j+3], v.w, a11);
            }
            float cn0 = cnL[c], cn1 = cnL[c + 1];
            float d00 = (rr0 - 2.0f * a00) + cn0;
            float d01 = (rr0 - 2.0f * a01) + cn1;
            float d10 = (rr1 - 2.0f * a10) + cn0;
            float d11 = (rr1 - 2.0f * a11) + cn1;
            if (d00 < bd0) { bd0 = d00; bi0 = c; }
            if (d01 < bd0) { bd0 = d01; bi0 = c + 1; }
            if (d10 < bd1) { bd1 = d10; bi1 = c; }
            if (d11 < bd1) { bd1 = d11; bi1 = c + 1; }
        }

        sd0[w][l] = bd0; si0[w][l] = bi0;
        sd1[w][l] = bd1; si1[w][l] = bi1;
        __syncthreads();

        float g0 = sd0[0][l]; int gi0 = si0[0][l];
        float g1 = sd1[0][l]; int gi1 = si1[0][l];
        #pragma unroll
        for (int ww = 1; ww < 4; ++ww) {
            float od = sd0[ww][l]; int oi = si0[ww][l];
            if (od < g0 || (od == g0 && oi < gi0)) { g0 = od; gi0 = oi; }
            od = sd1[ww][l]; oi = si1[ww][l];
            if (od < g1 || (od == g1 && oi < gi1)) { g1 = od; gi1 = oi; }
        }
        bidx0[q] = gi0;
        bidx1[q] = gi1;

        {
            const float4* p0 = reinterpret_cast<const float4*>(cbL + (gi0 << 5));
            const float4* p1 = reinterpret_cast<const float4*>(cbL + (gi1 << 5));
            float cs0 = 0.f, cs1 = 0.f;
            #pragma unroll
            for (int j = 0; j < 8; ++j) {
                float4 v0 = p0[j], v1 = p1[j];
                float df;
                df = v0.x - r0[4*j+0]; cs0 = fmaf(df, df, cs0); r0[4*j+0] = r0[4*j+0] - v0.x;
                df = v0.y - r0[4*j+1]; cs0 = fmaf(df, df, cs0); r0[4*j+1] = r0[4*j+1] - v0.y;
                df = v0.z - r0[4*j+2]; cs0 = fmaf(df, df, cs0); r0[4*j+2] = r0[4*j+2] - v0.z;
                df = v0.w - r0[4*j+3]; cs0 = fmaf(df, df, cs0); r0[4*j+3] = r0[4*j+3] - v0.w;
                df = v1.x - r1[4*j+0]; cs1 = fmaf(df, df, cs1); r1[4*j+0] = r1[4*j+0] - v1.x;
                df = v1.y - r1[4*j+1]; cs1 = fmaf(df, df, cs1); r1[4*j+1] = r1[4*j+1] - v1.y;
                df = v1.z - r1[4*j+2]; cs1 = fmaf(df, df, cs1); r1[4*j+2] = r1[4*j+2] - v1.z;
                df = v1.w - r1[4*j+3]; cs1 = fmaf(df, df, cs1); r1[4*j+3] = r1[4*j+3] - v1.w;
            }
            if (w == 0) { cAcc += (double)cs0; cAcc += (double)cs1; }
        }
    }

    if (w == 0) {
        float4 iv0 = make_float4((float)bidx0[0], (float)bidx0[1], (float)bidx0[2], (float)bidx0[3]);
        float4 iv1 = make_float4((float)bidx1[0], (float)bidx1[1], (float)bidx1[2], (float)bidx1[3]);
        *reinterpret_cast<float4*>(idxOut + grow0 * Q_ST) = iv0;
        *reinterpret_cast<float4*>(idxOut + grow1 * Q_ST) = iv1;

        const float4* zp0 = reinterpret_cast<const float4*>(zbuf + lrow0 * L_DIM);
        const float4* zp1 = reinterpret_cast<const float4*>(zbuf + lrow1 * L_DIM);
        ushort zq0[L_DIM], zq1[L_DIM];
        #pragma unroll
        for (int j = 0; j < 8; ++j) {
            float4 a = zp0[j], b = zp1[j];
            zq0[4*j+0] = f2bf(a.x - r0[4*j+0]);
            zq0[4*j+1] = f2bf(a.y - r0[4*j+1]);
            zq0[4*j+2] = f2bf(a.z - r0[4*j+2]);
            zq0[4*j+3] = f2bf(a.w - r0[4*j+3]);
            zq1[4*j+0] = f2bf(b.x - r1[4*j+0]);
            zq1[4*j+1] = f2bf(b.y - r1[4*j+1]);
            zq1[4*j+2] = f2bf(b.z - r1[4*j+2]);
            zq1[4*j+3] = f2bf(b.w - r1[4*j+3]);
        }
        uint4* o0 = reinterpret_cast<uint4*>(zqb + lrow0 * L_DIM);
        uint4* o1 = reinterpret_cast<uint4*>(zqb + lrow1 * L_DIM);
        const uint4* s0 = reinterpret_cast<const uint4*>(zq0);
        const uint4* s1 = reinterpret_cast<const uint4*>(zq1);
        #pragma unroll
        for (int j = 0; j < 4; ++j) { o0[j] = s0[j]; o1[j] = s1[j]; }
    }

    sred[t] = (w == 0) ? cAcc : 0.0;
    __syncthreads();
    for (int s = 128; s > 0; s >>= 1) {
        if (t < s) sred[t] += sred[t + s];
        __syncthreads();
    }
    if (t == 0) commitPart[rowBase / VQ_RPB + blockIdx.x] = sred[0];
}

// ---------------- bf16 MFMA GEMM (decoder; r6 version) ----------------------------
template<bool RELU, bool OUTBF16>
__global__ __launch_bounds__(256)
void mfma_gemm(const ushort* __restrict__ A, const ushort* __restrict__ Bt,
               const float* __restrict__ bias, void* __restrict__ Cout,
               int K, int Nout)
{
    __shared__ ushort As[128][40];
    __shared__ ushort Bs[128][40];
    const int t    = threadIdx.x;
    const int lane = t & 63;
    const int wid  = t >> 6;
    const int wr = wid >> 1, wc = wid & 1;
    const size_t row0 = (size_t)blockIdx.x * 128;
    const int    col0 = blockIdx.y * 128;

    f32x4 acc[4][4] = {};
    const int srow = t >> 1;
    const int sh   = (t & 1) << 4;

    for (int k0 = 0; k0 < K; k0 += 32) {
        {
            const ushort* ap = A + (row0 + srow) * (size_t)K + k0 + sh;
            uint4 v0 = *reinterpret_cast<const uint4*>(ap);
            uint4 v1 = *reinterpret_cast<const uint4*>(ap + 8);
            *reinterpret_cast<uint4*>(&As[srow][sh])     = v0;
            *reinterpret_cast<uint4*>(&As[srow][sh + 8]) = v1;
            const ushort* bp = Bt + (size_t)(col0 + srow) * K + k0 + sh;
            uint4 w0 = *reinterpret_cast<const uint4*>(bp);
            uint4 w1 = *reinterpret_cast<const uint4*>(bp + 8);
            *reinterpret_cast<uint4*>(&Bs[srow][sh])     = w0;
            *reinterpret_cast<uint4*>(&Bs[srow][sh + 8]) = w1;
        }
        __syncthreads();
        const int l15 = lane & 15, lk = (lane >> 4) << 3;
        short8v af[4], bf[4];
        #pragma unroll
        for (int f = 0; f < 4; ++f) {
            af[f] = *reinterpret_cast<const short8v*>(&As[(wr << 6) + (f << 4) + l15][lk]);
            bf[f] = *reinterpret_cast<const short8v*>(&Bs[(wc << 6) + (f << 4) + l15][lk]);
        }
        #pragma unroll
        for (int i = 0; i < 4; ++i)
            #pragma unroll
            for (int j = 0; j < 4; ++j)
                acc[i][j] = __builtin_amdgcn_mfma_f32_16x16x32_bf16(af[i], bf[j], acc[i][j], 0, 0, 0);
        __syncthreads();
    }

    const int l15 = lane & 15, lr4 = (lane >> 4) << 2;
    #pragma unroll
    for (int i = 0; i < 4; ++i) {
        #pragma unroll
        for (int j = 0; j < 4; ++j) {
            int col = col0 + (wc << 6) + (j << 4) + l15;
            float bv = bias[col];
            #pragma unroll
            for (int rj = 0; rj < 4; ++rj) {
                size_t row = row0 + (wr << 6) + (i << 4) + lr4 + rj;
                float v = acc[i][j][rj] + bv;
                if (RELU) v = fmaxf(v, 0.f);
                if (OUTBF16)
                    reinterpret_cast<ushort*>(Cout)[row * Nout + col] = f2bf(v);
                else
                    reinterpret_cast<float*>(Cout)[row * Nout + col] = v;
            }
        }
    }
}

// ---------------- final commit reduction (1024 partials) --------------------------
__global__ __launch_bounds__(256)
void commit_finalize(const double* __restrict__ commitPart, float* __restrict__ outCommit)
{
    __shared__ double sred[256];
    const int t = threadIdx.x;
    double s = 0.0;
    for (int i = t; i < NPART; i += 256) s += commitPart[i];
    sred[t] = s;
    __syncthreads();
    for (int st = 128; st > 0; st >>= 1) {
        if (t < st) sred[t] += sred[t + st];
        __syncthreads();
    }
    if (t == 0)
        outCommit[0] = (float)(sred[0] / ((double)N_ROWS * (double)L_DIM));
}

extern "C" void kernel_launch(void* const* d_in, const int* in_sizes, int n_in,
                              void* d_out, int out_size, void* d_ws, size_t ws_size,
                              hipStream_t stream)
{
    const float* x      = (const float*)d_in[0];
    const float* enc_w1 = (const float*)d_in[1];
    const float* enc_b1 = (const float*)d_in[2];
    const float* enc_w2 = (const float*)d_in[3];
    const float* enc_b2 = (const float*)d_in[4];
    const float* enc_w3 = (const float*)d_in[5];
    const float* enc_b3 = (const float*)d_in[6];
    const float* dec_w1 = (const float*)d_in[7];
    const float* dec_b1 = (const float*)d_in[8];
    const float* dec_w2 = (const float*)d_in[9];
    const float* dec_b2 = (const float*)d_in[10];
    const float* dec_w3 = (const float*)d_in[11];
    const float* dec_b3 = (const float*)d_in[12];
    const float* cbs    = (const float*)d_in[13];

    float* out       = (float*)d_out;
    float* xrec      = out;
    float* idxOut    = out + (size_t)N_ROWS * D_IN;
    float* commitOut = idxOut + (size_t)N_ROWS * Q_ST;

    // ws layout:
    //   cnorm  f32[2048]     @0      (8192)
    //   commit f64[1024]     @8192   (8192)
    //   w1t    u16[256*32]   @16384  (16384)
    //   w2t    u16[256*256]  @32768  (131072)
    //   w3t    u16[384*256]  @163840 (196608)
    //   bufs                 @360448
    char*   wsb        = (char*)d_ws;
    float*  cnorm      = (float*)wsb;
    double* commitPart = (double*)(wsb + 8192);
    ushort* w1t        = (ushort*)(wsb + 16384);
    ushort* w2t        = (ushort*)(wsb + 32768);
    ushort* w3t        = (ushort*)(wsb + 163840);
    char*   bufs       = wsb + 360448;

    // per-row bytes: zbuf 128 + bufA 1024 + bufB 1024 + zqb 64 + h1b 512 + h2b 512 = 3264
    size_t availB = (ws_size > 360448) ? ws_size - 360448 : 0;
    long long chunk = (long long)(availB / 3264);
    chunk = (chunk / 256) * 256;
    if (chunk > N_ROWS) chunk = N_ROWS;
    if (chunk < 256) chunk = 256;

    float*  zbuf = (float*)bufs;
    float*  bufA = zbuf + (size_t)chunk * L_DIM;
    float*  bufB = bufA + (size_t)chunk * H_DIM;
    ushort* zqb  = (ushort*)(bufB + (size_t)chunk * H_DIM);
    ushort* h1b  = zqb + (size_t)chunk * L_DIM;
    ushort* h2b  = h1b + (size_t)chunk * H_DIM;

    cnorm_kernel<<<8, 256, 0, stream>>>(cbs, cnorm);
    prep_wt<<<(L_DIM  * H_DIM + 255) / 256, 256, 0, stream>>>(dec_w1, w1t, L_DIM, H_DIM);
    prep_wt<<<(H_DIM * H_DIM + 255) / 256, 256, 0, stream>>>(dec_w2, w2t, H_DIM, H_DIM);
    prep_wt<<<(H_DIM * D_IN + 255) / 256, 256, 0, stream>>>(dec_w3, w3t, H_DIM, D_IN);

    for (long long ro = 0; ro < N_ROWS; ro += chunk) {
        long long R = N_ROWS - ro;
        if (R > chunk) R = chunk;
        unsigned g1 = (unsigned)(R / 128);
        dim3 g2(g1, 2);
        dim3 g3(g1, 3);
        // encoder (bit-exact fp32; 128x256 tile, BK=16)
        gemm_bias<true><<<g1, 256, 0, stream>>>(x + ro * D_IN, enc_w1, enc_b1, bufA, D_IN);
        gemm_bias<true><<<g1, 256, 0, stream>>>(bufA, enc_w2, enc_b2, bufB, H_DIM);
        gemm_z<<<g1, 256, 0, stream>>>(bufB, enc_w3, enc_b3, zbuf);
        // residual VQ (bit-exact; writes bf16 z_q)
        vq9_kernel<<<(unsigned)(R / VQ_RPB), 256, 0, stream>>>(zbuf, cbs, cnorm, zqb,
                                                               idxOut, commitPart, (int)ro);
        // decoder (bf16 MFMA)
        mfma_gemm<true,  true ><<<g2, 256, 0, stream>>>(zqb, w1t, dec_b1, h1b, L_DIM, H_DIM);
        mfma_gemm<true,  true ><<<g2, 256, 0, stream>>>(h1b, w2t, dec_b2, h2b, H_DIM, H_DIM);
        mfma_gemm<false, false><<<g3, 256, 0, stream>>>(h2b, w3t, dec_b3, xrec + ro * D_IN, H_DIM, D_IN);
    }

    commit_finalize<<<1, 256, 0, stream>>>(commitPart, commitOut);
}

// Round 16
// 918.633 us; speedup vs baseline: 1.3362x; 1.0042x over previous
//
#include <hip/hip_runtime.h>
#include <hip/hip_bf16.h>
#include <math.h>

// RQ-VAE pipeline. Index path = numpy-fp32 bit-exact (validated r3-r15).
// Round 16: vq10 — 4 rows/lane (VQ_RPB=256): each broadcast codebook ds_read
// feeds 4 rows' FMA chains (FMA:DS = 16:1, DS latency hidden within a wave).
// Same 4-wave col-split + lexicographic merge + replicated residual update
// (bit-exactness rules validated r4/r9/r11). LDS 76KB -> 2 blocks/CU,
// launch_bounds(256,2) -> 256-VGPR budget for the 4x32 residual arrays.
// Encoder / gemm_z / decoder / prep = r15.

#define N_ROWS 131072
#define D_IN   384
#define H_DIM  256
#define L_DIM  32
#define K_CB   512
#define Q_ST   4
#define VQ_RPB 256                 // rows per VQ block
#define NPART  (N_ROWS / VQ_RPB)   // 512 commit partials

typedef __attribute__((ext_vector_type(8))) short short8v;
typedef __attribute__((ext_vector_type(4))) float f32x4;

__device__ __forceinline__ ushort f2bf(float v)
{
    __hip_bfloat16 b = __float2bfloat16(v);
    return *reinterpret_cast<ushort*>(&b);
}

// np.sum(v*v) for n=32: numpy pairwise 8-accumulator order, products pre-rounded.
__device__ __forceinline__ float np_sumsq32(const float* __restrict__ v)
{
    #pragma clang fp contract(off)
    float s0 = v[0]*v[0], s1 = v[1]*v[1], s2 = v[2]*v[2], s3 = v[3]*v[3];
    float s4 = v[4]*v[4], s5 = v[5]*v[5], s6 = v[6]*v[6], s7 = v[7]*v[7];
    s0 = s0 + v[8]*v[8];   s1 = s1 + v[9]*v[9];   s2 = s2 + v[10]*v[10]; s3 = s3 + v[11]*v[11];
    s4 = s4 + v[12]*v[12]; s5 = s5 + v[13]*v[13]; s6 = s6 + v[14]*v[14]; s7 = s7 + v[15]*v[15];
    s0 = s0 + v[16]*v[16]; s1 = s1 + v[17]*v[17]; s2 = s2 + v[18]*v[18]; s3 = s3 + v[19]*v[19];
    s4 = s4 + v[20]*v[20]; s5 = s5 + v[21]*v[21]; s6 = s6 + v[22]*v[22]; s7 = s7 + v[23]*v[23];
    s0 = s0 + v[24]*v[24]; s1 = s1 + v[25]*v[25]; s2 = s2 + v[26]*v[26]; s3 = s3 + v[27]*v[27];
    s4 = s4 + v[28]*v[28]; s5 = s5 + v[29]*v[29]; s6 = s6 + v[30]*v[30]; s7 = s7 + v[31]*v[31];
    return ((s0 + s1) + (s2 + s3)) + ((s4 + s5) + (s6 + s7));
}

// ---------------- fp32 tiled GEMM (encoder; bit-exact path; BK=16; r15) -----------
template<bool RELU>
__global__ __launch_bounds__(256, 2)
void gemm_bias(const float* __restrict__ A, const float* __restrict__ B,
               const float* __restrict__ bias, float* __restrict__ C,
               int K)
{
    #pragma clang fp contract(off)
    __shared__ float As2[16][133];   // [k][row], pad 133
    __shared__ float Bs[16][256];    // [k][col]
    const int t  = threadIdx.x;
    const int tc = t & 15;
    const int tr = t >> 4;
    const size_t row0 = (size_t)blockIdx.x * 128;

    float acc[8][16];
    #pragma unroll
    for (int i = 0; i < 8; ++i)
        #pragma unroll
        for (int j = 0; j < 16; ++j) acc[i][j] = 0.f;

    const int ar = t >> 2, ak = (t & 3) << 2;
    const int brow = t >> 6, bcol = (t & 63) << 2;

    for (int k0 = 0; k0 < K; k0 += 16) {
        #pragma unroll
        for (int i = 0; i < 2; ++i) {
            int r = ar + (i << 6);
            float4 v = *reinterpret_cast<const float4*>(A + (row0 + r) * (size_t)K + k0 + ak);
            As2[ak + 0][r] = v.x; As2[ak + 1][r] = v.y;
            As2[ak + 2][r] = v.z; As2[ak + 3][r] = v.w;
        }
        #pragma unroll
        for (int i = 0; i < 4; ++i) {
            int rb = brow + (i << 2);
            float4 v = *reinterpret_cast<const float4*>(B + (size_t)(k0 + rb) * H_DIM + bcol);
            *reinterpret_cast<float4*>(&Bs[rb][bcol]) = v;
        }
        __syncthreads();
        #pragma unroll
        for (int k = 0; k < 16; ++k) {
            float a[8], b[16];
            *reinterpret_cast<float4*>(&a[0]) = *reinterpret_cast<const float4*>(&As2[k][tr << 3]);
            *reinterpret_cast<float4*>(&a[4]) = *reinterpret_cast<const float4*>(&As2[k][(tr << 3) + 4]);
            #pragma unroll
            for (int g = 0; g < 4; ++g)
                *reinterpret_cast<float4*>(&b[g << 2]) =
                    *reinterpret_cast<const float4*>(&Bs[k][(g << 6) + (tc << 2)]);
            #pragma unroll
            for (int i = 0; i < 8; ++i)
                #pragma unroll
                for (int j = 0; j < 16; ++j) acc[i][j] = fmaf(a[i], b[j], acc[i][j]);
        }
        __syncthreads();
    }

    #pragma unroll
    for (int i = 0; i < 8; ++i) {
        size_t r = row0 + (tr << 3) + i;
        #pragma unroll
        for (int g = 0; g < 4; ++g) {
            int c = (g << 6) + (tc << 2);
            float v[4];
            #pragma unroll
            for (int j = 0; j < 4; ++j) {
                float u = acc[i][(g << 2) + j] + bias[c + j];
                if (RELU) u = fmaxf(u, 0.0f);
                v[j] = u;
            }
            *reinterpret_cast<float4*>(C + r * H_DIM + c) = *reinterpret_cast<float4*>(&v[0]);
        }
    }
}

// ---------------- z-GEMM: Z[M,32] = A[M,256] @ W[256,32] + b (bit-exact) ----------
__global__ __launch_bounds__(256)
void gemm_z(const float* __restrict__ A, const float* __restrict__ W,
            const float* __restrict__ bv, float* __restrict__ Z)
{
    #pragma clang fp contract(off)
    __shared__ float As2[32][133];
    __shared__ float Ws[32][36];
    const int t = threadIdx.x;
    const int cgz = t & 7, rgz = t >> 3;
    const size_t row0 = (size_t)blockIdx.x * 128;

    float acc[4][4];
    #pragma unroll
    for (int i = 0; i < 4; ++i)
        #pragma unroll
        for (int j = 0; j < 4; ++j) acc[i][j] = 0.f;

    const int ar = t >> 3, ak = (t & 7) << 2;
    for (int k0 = 0; k0 < H_DIM; k0 += 32) {
        #pragma unroll
        for (int i = 0; i < 4; ++i) {
            int r = ar + (i << 5);
            float4 v = *reinterpret_cast<const float4*>(A + (row0 + r) * (size_t)H_DIM + k0 + ak);
            As2[ak + 0][r] = v.x; As2[ak + 1][r] = v.y;
            As2[ak + 2][r] = v.z; As2[ak + 3][r] = v.w;
        }
        {
            int kr = t >> 3, cc = (t & 7) << 2;
            float4 v = *reinterpret_cast<const float4*>(W + (size_t)(k0 + kr) * L_DIM + cc);
            *reinterpret_cast<float4*>(&Ws[kr][cc]) = v;
        }
        __syncthreads();
        #pragma unroll
        for (int k = 0; k < 32; ++k) {
            float a[4], w[4];
            *reinterpret_cast<float4*>(&a[0]) = *reinterpret_cast<const float4*>(&As2[k][rgz << 2]);
            *reinterpret_cast<float4*>(&w[0]) = *reinterpret_cast<const float4*>(&Ws[k][cgz << 2]);
            #pragma unroll
            for (int i = 0; i < 4; ++i)
                #pragma unroll
                for (int j = 0; j < 4; ++j) acc[i][j] = fmaf(a[i], w[j], acc[i][j]);
        }
        __syncthreads();
    }
    #pragma unroll
    for (int i = 0; i < 4; ++i) {
        size_t row = row0 + (rgz << 2) + i;
        float v[4];
        #pragma unroll
        for (int j = 0; j < 4; ++j) v[j] = acc[i][j] + bv[(cgz << 2) + j];
        *reinterpret_cast<float4*>(Z + row * L_DIM + (cgz << 2)) = *reinterpret_cast<float4*>(&v[0]);
    }
}

// ---------------- cnorm (numpy order) ---------------------------------------------
__global__ __launch_bounds__(256)
void cnorm_kernel(const float* __restrict__ cbs, float* __restrict__ cnorm)
{
    #pragma clang fp contract(off)
    int g = blockIdx.x * 256 + threadIdx.x;
    const float* c = cbs + (size_t)g * L_DIM;
    float cl[L_DIM];
    #pragma unroll
    for (int l = 0; l < L_DIM; ++l) cl[l] = c[l];
    cnorm[g] = np_sumsq32(cl);
}

// ---------------- dec-weight prep: fp32 [K][N] -> bf16 transposed [N][K] ----------
__global__ __launch_bounds__(256)
void prep_wt(const float* __restrict__ W, ushort* __restrict__ Wt, int K, int N)
{
    int g = blockIdx.x * 256 + threadIdx.x;
    if (g >= K * N) return;
    int n = g / K, k = g - n * K;
    Wt[g] = f2bf(W[(size_t)k * N + n]);
}

// ---------------- residual VQ v10: 4 rows/lane + 4-wave col-split -----------------
// Block: 256 thr = 4 waves; 256 rows (lane l owns rows l, l+64, l+128, l+192;
// same rows in every wave). Full 64KB codebook + cnorm in LDS. Wave w scans
// cols [128w,128w+128): each broadcast ds_read feeds 4 rows (FMA:DS = 16:1).
// Cross-wave merge lexicographic (d,idx) == np first-min; residual update
// replicated in all waves (deterministic). 512 blocks -> 2/CU resident.
__global__ __launch_bounds__(256, 2)
void vq10_kernel(const float* __restrict__ zbuf, const float* __restrict__ cbs,
                 const float* __restrict__ cnorm_g, ushort* __restrict__ zqb,
                 float* __restrict__ idxOut, double* __restrict__ commitPart,
                 int rowBase)
{
    #pragma clang fp contract(off)
    __shared__ float  cbL[K_CB * L_DIM];   // 64 KB
    __shared__ float  cnL[K_CB];           // 2 KB
    __shared__ float  sdM[4][4][64];       // [rowset][wave][lane] 4 KB
    __shared__ int    siM[4][4][64];       // 4 KB
    __shared__ double sred[256];           // 2 KB

    const int t = threadIdx.x;
    const int w = t >> 6;
    const int l = t & 63;
    const size_t lr0 = (size_t)blockIdx.x * VQ_RPB + l;
    const size_t lr1 = lr0 + 64, lr2 = lr0 + 128, lr3 = lr0 + 192;
    const int c0 = w << 7;

    float r0[L_DIM], r1[L_DIM], r2[L_DIM], r3[L_DIM];
    {
        const float4* z0 = reinterpret_cast<const float4*>(zbuf + lr0 * L_DIM);
        const float4* z1 = reinterpret_cast<const float4*>(zbuf + lr1 * L_DIM);
        const float4* z2 = reinterpret_cast<const float4*>(zbuf + lr2 * L_DIM);
        const float4* z3 = reinterpret_cast<const float4*>(zbuf + lr3 * L_DIM);
        #pragma unroll
        for (int j = 0; j < 8; ++j) {
            float4 a = z0[j], b = z1[j], c = z2[j], d = z3[j];
            r0[4*j+0]=a.x; r0[4*j+1]=a.y; r0[4*j+2]=a.z; r0[4*j+3]=a.w;
            r1[4*j+0]=b.x; r1[4*j+1]=b.y; r1[4*j+2]=b.z; r1[4*j+3]=b.w;
            r2[4*j+0]=c.x; r2[4*j+1]=c.y; r2[4*j+2]=c.z; r2[4*j+3]=c.w;
            r3[4*j+0]=d.x; r3[4*j+1]=d.y; r3[4*j+2]=d.z; r3[4*j+3]=d.w;
        }
    }

    int bx0[Q_ST], bx1[Q_ST], bx2[Q_ST], bx3[Q_ST];
    double cAcc = 0.0;

    #pragma unroll 1
    for (int q = 0; q < Q_ST; ++q) {
        __syncthreads();
        {
            const float4* src = reinterpret_cast<const float4*>(cbs + (size_t)q * K_CB * L_DIM);
            float4* dst = reinterpret_cast<float4*>(cbL);
            #pragma unroll
            for (int i = 0; i < 16; ++i) dst[t + (i << 8)] = src[t + (i << 8)];
            cnL[t]       = cnorm_g[q * K_CB + t];
            cnL[t + 256] = cnorm_g[q * K_CB + t + 256];
        }
        __syncthreads();

        float rr0 = np_sumsq32(r0), rr1 = np_sumsq32(r1);
        float rr2 = np_sumsq32(r2), rr3 = np_sumsq32(r3);
        float bd0 = __builtin_inff(), bd1 = __builtin_inff();
        float bd2 = __builtin_inff(), bd3 = __builtin_inff();
        int   bi0 = c0, bi1 = c0, bi2 = c0, bi3 = c0;

        #pragma unroll 1
        for (int cc = 0; cc < 128; cc += 2) {
            const int c = c0 + cc;
            const float4* w0 = reinterpret_cast<const float4*>(cbL + (c << 5));
            const float4* w1 = w0 + 8;
            float a00=0.f,a01=0.f, a10=0.f,a11=0.f, a20=0.f,a21=0.f, a30=0.f,a31=0.f;
            #pragma unroll
            for (int j = 0; j < 8; ++j) {
                float4 u = w0[j], v = w1[j];   // broadcast; feeds 4 rows
                a00=fmaf(r0[4*j+0],u.x,a00); a01=fmaf(r0[4*j+0],v.x,a01);
                a10=fmaf(r1[4*j+0],u.x,a10); a11=fmaf(r1[4*j+0],v.x,a11);
                a20=fmaf(r2[4*j+0],u.x,a20); a21=fmaf(r2[4*j+0],v.x,a21);
                a30=fmaf(r3[4*j+0],u.x,a30); a31=fmaf(r3[4*j+0],v.x,a31);
                a00=fmaf(r0[4*j+1],u.y,a00); a01=fmaf(r0[4*j+1],v.y,a01);
                a10=fmaf(r1[4*j+1],u.y,a10); a11=fmaf(r1[4*j+1],v.y,a11);
                a20=fmaf(r2[4*j+1],u.y,a20); a21=fmaf(r2[4*j+1],v.y,a21);
                a30=fmaf(r3[4*j+1],u.y,a30); a31=fmaf(r3[4*j+1],v.y,a31);
                a00=fmaf(r0[4*j+2],u.z,a00); a01=fmaf(r0[4*j+2],v.z,a01);
                a10=fmaf(r1[4*j+2],u.z,a10); a11=fmaf(r1[4*j+2],v.z,a11);
                a20=fmaf(r2[4*j+2],u.z,a20); a21=fmaf(r2[4*j+2],v.z,a21);
                a30=fmaf(r3[4*j+2],u.z,a30); a31=fmaf(r3[4*j+2],v.z,a31);
                a00=fmaf(r0[4*j+3],u.w,a00); a01=fmaf(r0[4*j+3],v.w,a01);
                a10=fmaf(r1[4*j+3],u.w,a10); a11=fmaf(r1[4*j+3],v.w,a11);
                a20=fmaf(r2[4*j+3],u.w,a20); a21=fmaf(r2[4*j+3],v.w,a21);
                a30=fmaf(r3[4*j+3],u.w,a30); a31=fmaf(r3[4*j+3],v.w,a31);
            }
            float cn0 = cnL[c], cn1 = cnL[c + 1];
            float d00 = (rr0 - 2.0f*a00) + cn0, d01 = (rr0 - 2.0f*a01) + cn1;
            float d10 = (rr1 - 2.0f*a10) + cn0, d11 = (rr1 - 2.0f*a11) + cn1;
            float d20 = (rr2 - 2.0f*a20) + cn0, d21 = (rr2 - 2.0f*a21) + cn1;
            float d30 = (rr3 - 2.0f*a30) + cn0, d31 = (rr3 - 2.0f*a31) + cn1;
            if (d00 < bd0) { bd0 = d00; bi0 = c; }
            if (d01 < bd0) { bd0 = d01; bi0 = c + 1; }
            if (d10 < bd1) { bd1 = d10; bi1 = c; }
            if (d11 < bd1) { bd1 = d11; bi1 = c + 1; }
            if (d20 < bd2) { bd2 = d20; bi2 = c; }
            if (d21 < bd2) { bd2 = d21; bi2 = c + 1; }
            if (d30 < bd3) { bd3 = d30; bi3 = c; }
            if (d31 < bd3) { bd3 = d31; bi3 = c + 1; }
        }

        sdM[0][w][l] = bd0; siM[0][w][l] = bi0;
        sdM[1][w][l] = bd1; siM[1][w][l] = bi1;
        sdM[2][w][l] = bd2; siM[2][w][l] = bi2;
        sdM[3][w][l] = bd3; siM[3][w][l] = bi3;
        __syncthreads();

        int gi[4];
        #pragma unroll
        for (int s = 0; s < 4; ++s) {
            float g = sdM[s][0][l]; int gx = siM[s][0][l];
            #pragma unroll
            for (int ww = 1; ww < 4; ++ww) {
                float od = sdM[s][ww][l]; int oi = siM[s][ww][l];
                if (od < g || (od == g && oi < gx)) { g = od; gx = oi; }
            }
            gi[s] = gx;
        }
        bx0[q] = gi[0]; bx1[q] = gi[1]; bx2[q] = gi[2]; bx3[q] = gi[3];

        // winner gathers + residual/commit update (replicated in all waves)
        {
            const float4* p0 = reinterpret_cast<const float4*>(cbL + (gi[0] << 5));
            const float4* p1 = reinterpret_cast<const float4*>(cbL + (gi[1] << 5));
            const float4* p2 = reinterpret_cast<const float4*>(cbL + (gi[2] << 5));
            const float4* p3 = reinterpret_cast<const float4*>(cbL + (gi[3] << 5));
            float cs0 = 0.f, cs1 = 0.f, cs2 = 0.f, cs3 = 0.f;
            #pragma unroll
            for (int j = 0; j < 8; ++j) {
                float4 v0 = p0[j], v1 = p1[j], v2 = p2[j], v3 = p3[j];
                float df;
                df = v0.x - r0[4*j+0]; cs0 = fmaf(df, df, cs0); r0[4*j+0] = r0[4*j+0] - v0.x;
                df = v0.y - r0[4*j+1]; cs0 = fmaf(df, df, cs0); r0[4*j+1] = r0[4*j+1] - v0.y;
                df = v0.z - r0[4*j+2]; cs0 = fmaf(df, df, cs0); r0[4*j+2] = r0[4*j+2] - v0.z;
                df = v0.w - r0[4*j+3]; cs0 = fmaf(df, df, cs0); r0[4*j+3] = r0[4*j+3] - v0.w;
                df = v1.x - r1[4*j+0]; cs1 = fmaf(df, df, cs1); r1[4*j+0] = r1[4*j+0] - v1.x;
                df = v1.y - r1[4*j+1]; cs1 = fmaf(df, df, cs1); r1[4*j+1] = r1[4*j+1] - v1.y;
                df = v1.z - r1[4*j+2]; cs1 = fmaf(df, df, cs1); r1[4*j+2] = r1[4*j+2] - v1.z;
                df = v1.w - r1[4*j+3]; cs1 = fmaf(df, df, cs1); r1[4*j+3] = r1[4*j+3] - v1.w;
                df = v2.x - r2[4*j+0]; cs2 = fmaf(df, df, cs2); r2[4*j+0] = r2[4*j+0] - v2.x;
                df = v2.y - r2[4*j+1]; cs2 = fmaf(df, df, cs2); r2[4*j+1] = r2[4*j+1] - v2.y;
                df = v2.z - r2[4*j+2]; cs2 = fmaf(df, df, cs2); r2[4*j+2] = r2[4*j+2] - v2.z;
                df = v2.w - r2[4*j+3]; cs2 = fmaf(df, df, cs2); r2[4*j+3] = r2[4*j+3] - v2.w;
                df = v3.x - r3[4*j+0]; cs3 = fmaf(df, df, cs3); r3[4*j+0] = r3[4*j+0] - v3.x;
                df = v3.y - r3[4*j+1]; cs3 = fmaf(df, df, cs3); r3[4*j+1] = r3[4*j+1] - v3.y;
                df = v3.z - r3[4*j+2]; cs3 = fmaf(df, df, cs3); r3[4*j+2] = r3[4*j+2] - v3.z;
                df = v3.w - r3[4*j+3]; cs3 = fmaf(df, df, cs3); r3[4*j+3] = r3[4*j+3] - v3.w;
            }
            if (w == 0) {
                cAcc += (double)cs0; cAcc += (double)cs1;
                cAcc += (double)cs2; cAcc += (double)cs3;
            }
        }
    }

    if (w == 0) {
        const size_t g0 = (size_t)rowBase + lr0, g1 = (size_t)rowBase + lr1;
        const size_t g2 = (size_t)rowBase + lr2, g3 = (size_t)rowBase + lr3;
        *reinterpret_cast<float4*>(idxOut + g0 * Q_ST) =
            make_float4((float)bx0[0], (float)bx0[1], (float)bx0[2], (float)bx0[3]);
        *reinterpret_cast<float4*>(idxOut + g1 * Q_ST) =
            make_float4((float)bx1[0], (float)bx1[1], (float)bx1[2], (float)bx1[3]);
        *reinterpret_cast<float4*>(idxOut + g2 * Q_ST) =
            make_float4((float)bx2[0], (float)bx2[1], (float)bx2[2], (float)bx2[3]);
        *reinterpret_cast<float4*>(idxOut + g3 * Q_ST) =
            make_float4((float)bx3[0], (float)bx3[1], (float)bx3[2], (float)bx3[3]);

        // z_q = z - r_final (re-read z), bf16 out
        const float4* z0 = reinterpret_cast<const float4*>(zbuf + lr0 * L_DIM);
        const float4* z1 = reinterpret_cast<const float4*>(zbuf + lr1 * L_DIM);
        const float4* z2 = reinterpret_cast<const float4*>(zbuf + lr2 * L_DIM);
        const float4* z3 = reinterpret_cast<const float4*>(zbuf + lr3 * L_DIM);
        ushort q0[L_DIM], q1[L_DIM], q2[L_DIM], q3[L_DIM];
        #pragma unroll
        for (int j = 0; j < 8; ++j) {
            float4 a = z0[j], b = z1[j], c = z2[j], d = z3[j];
            q0[4*j+0]=f2bf(a.x-r0[4*j+0]); q0[4*j+1]=f2bf(a.y-r0[4*j+1]);
            q0[4*j+2]=f2bf(a.z-r0[4*j+2]); q0[4*j+3]=f2bf(a.w-r0[4*j+3]);
            q1[4*j+0]=f2bf(b.x-r1[4*j+0]); q1[4*j+1]=f2bf(b.y-r1[4*j+1]);
            q1[4*j+2]=f2bf(b.z-r1[4*j+2]); q1[4*j+3]=f2bf(b.w-r1[4*j+3]);
            q2[4*j+0]=f2bf(c.x-r2[4*j+0]); q2[4*j+1]=f2bf(c.y-r2[4*j+1]);
            q2[4*j+2]=f2bf(c.z-r2[4*j+2]); q2[4*j+3]=f2bf(c.w-r2[4*j+3]);
            q3[4*j+0]=f2bf(d.x-r3[4*j+0]); q3[4*j+1]=f2bf(d.y-r3[4*j+1]);
            q3[4*j+2]=f2bf(d.z-r3[4*j+2]); q3[4*j+3]=f2bf(d.w-r3[4*j+3]);
        }
        uint4* o0 = reinterpret_cast<uint4*>(zqb + lr0 * L_DIM);
        uint4* o1 = reinterpret_cast<uint4*>(zqb + lr1 * L_DIM);
        uint4* o2 = reinterpret_cast<uint4*>(zqb + lr2 * L_DIM);
        uint4* o3 = reinterpret_cast<uint4*>(zqb + lr3 * L_DIM);
        #pragma unroll
        for (int j = 0; j < 4; ++j) {
            o0[j] = reinterpret_cast<const uint4*>(q0)[j];
            o1[j] = reinterpret_cast<const uint4*>(q1)[j];
            o2[j] = reinterpret_cast<const uint4*>(q2)[j];
            o3[j] = reinterpret_cast<const uint4*>(q3)[j];
        }
    }

    sred[t] = (w == 0) ? cAcc : 0.0;
    __syncthreads();
    for (int s = 128; s > 0; s >>= 1) {
        if (t < s) sred[t] += sred[t + s];
        __syncthreads();
    }
    if (t == 0) commitPart[rowBase / VQ_RPB + blockIdx.x] = sred[0];
}

// ---------------- bf16 MFMA GEMM (decoder; r6 version) ----------------------------
template<bool RELU, bool OUTBF16>
__global__ __launch_bounds__(256)
void mfma_gemm(const ushort* __restrict__ A, const ushort* __restrict__ Bt,
               const float* __restrict__ bias, void* __restrict__ Cout,
               int K, int Nout)
{
    __shared__ ushort As[128][40];
    __shared__ ushort Bs[128][40];
    const int t    = threadIdx.x;
    const int lane = t & 63;
    const int wid  = t >> 6;
    const int wr = wid >> 1, wc = wid & 1;
    const size_t row0 = (size_t)blockIdx.x * 128;
    const int    col0 = blockIdx.y * 128;

    f32x4 acc[4][4] = {};
    const int srow = t >> 1;
    const int sh   = (t & 1) << 4;

    for (int k0 = 0; k0 < K; k0 += 32) {
        {
            const ushort* ap = A + (row0 + srow) * (size_t)K + k0 + sh;
            uint4 v0 = *reinterpret_cast<const uint4*>(ap);
            uint4 v1 = *reinterpret_cast<const uint4*>(ap + 8);
            *reinterpret_cast<uint4*>(&As[srow][sh])     = v0;
            *reinterpret_cast<uint4*>(&As[srow][sh + 8]) = v1;
            const ushort* bp = Bt + (size_t)(col0 + srow) * K + k0 + sh;
            uint4 w0 = *reinterpret_cast<const uint4*>(bp);
            uint4 w1 = *reinterpret_cast<const uint4*>(bp + 8);
            *reinterpret_cast<uint4*>(&Bs[srow][sh])     = w0;
            *reinterpret_cast<uint4*>(&Bs[srow][sh + 8]) = w1;
        }
        __syncthreads();
        const int l15 = lane & 15, lk = (lane >> 4) << 3;
        short8v af[4], bf[4];
        #pragma unroll
        for (int f = 0; f < 4; ++f) {
            af[f] = *reinterpret_cast<const short8v*>(&As[(wr << 6) + (f << 4) + l15][lk]);
            bf[f] = *reinterpret_cast<const short8v*>(&Bs[(wc << 6) + (f << 4) + l15][lk]);
        }
        #pragma unroll
        for (int i = 0; i < 4; ++i)
            #pragma unroll
            for (int j = 0; j < 4; ++j)
                acc[i][j] = __builtin_amdgcn_mfma_f32_16x16x32_bf16(af[i], bf[j], acc[i][j], 0, 0, 0);
        __syncthreads();
    }

    const int l15 = lane & 15, lr4 = (lane >> 4) << 2;
    #pragma unroll
    for (int i = 0; i < 4; ++i) {
        #pragma unroll
        for (int j = 0; j < 4; ++j) {
            int col = col0 + (wc << 6) + (j << 4) + l15;
            float bv = bias[col];
            #pragma unroll
            for (int rj = 0; rj < 4; ++rj) {
                size_t row = row0 + (wr << 6) + (i << 4) + lr4 + rj;
                float v = acc[i][j][rj] + bv;
                if (RELU) v = fmaxf(v, 0.f);
                if (OUTBF16)
                    reinterpret_cast<ushort*>(Cout)[row * Nout + col] = f2bf(v);
                else
                    reinterpret_cast<float*>(Cout)[row * Nout + col] = v;
            }
        }
    }
}

// ---------------- final commit reduction (512 partials) ---------------------------
__global__ __launch_bounds__(256)
void commit_finalize(const double* __restrict__ commitPart, float* __restrict__ outCommit)
{
    __shared__ double sred[256];
    const int t = threadIdx.x;
    double s = 0.0;
    for (int i = t; i < NPART; i += 256) s += commitPart[i];
    sred[t] = s;
    __syncthreads();
    for (int st = 128; st > 0; st >>= 1) {
        if (t < st) sred[t] += sred[t + st];
        __syncthreads();
    }
    if (t == 0)
        outCommit[0] = (float)(sred[0] / ((double)N_ROWS * (double)L_DIM));
}

extern "C" void kernel_launch(void* const* d_in, const int* in_sizes, int n_in,
                              void* d_out, int out_size, void* d_ws, size_t ws_size,
                              hipStream_t stream)
{
    const float* x      = (const float*)d_in[0];
    const float* enc_w1 = (const float*)d_in[1];
    const float* enc_b1 = (const float*)d_in[2];
    const float* enc_w2 = (const float*)d_in[3];
    const float* enc_b2 = (const float*)d_in[4];
    const float* enc_w3 = (const float*)d_in[5];
    const float* enc_b3 = (const float*)d_in[6];
    const float* dec_w1 = (const float*)d_in[7];
    const float* dec_b1 = (const float*)d_in[8];
    const float* dec_w2 = (const float*)d_in[9];
    const float* dec_b2 = (const float*)d_in[10];
    const float* dec_w3 = (const float*)d_in[11];
    const float* dec_b3 = (const float*)d_in[12];
    const float* cbs    = (const float*)d_in[13];

    float* out       = (float*)d_out;
    float* xrec      = out;
    float* idxOut    = out + (size_t)N_ROWS * D_IN;
    float* commitOut = idxOut + (size_t)N_ROWS * Q_ST;

    // ws layout:
    //   cnorm  f32[2048]     @0      (8192)
    //   commit f64[512]      @8192   (4096; pad to 16384)
    //   w1t    u16[256*32]   @16384  (16384)
    //   w2t    u16[256*256]  @32768  (131072)
    //   w3t    u16[384*256]  @163840 (196608)
    //   bufs                 @360448
    char*   wsb        = (char*)d_ws;
    float*  cnorm      = (float*)wsb;
    double* commitPart = (double*)(wsb + 8192);
    ushort* w1t        = (ushort*)(wsb + 16384);
    ushort* w2t        = (ushort*)(wsb + 32768);
    ushort* w3t        = (ushort*)(wsb + 163840);
    char*   bufs       = wsb + 360448;

    // per-row bytes: zbuf 128 + bufA 1024 + bufB 1024 + zqb 64 + h1b 512 + h2b 512 = 3264
    size_t availB = (ws_size > 360448) ? ws_size - 360448 : 0;
    long long chunk = (long long)(availB / 3264);
    chunk = (chunk / 256) * 256;
    if (chunk > N_ROWS) chunk = N_ROWS;
    if (chunk < 256) chunk = 256;

    float*  zbuf = (float*)bufs;
    float*  bufA = zbuf + (size_t)chunk * L_DIM;
    float*  bufB = bufA + (size_t)chunk * H_DIM;
    ushort* zqb  = (ushort*)(bufB + (size_t)chunk * H_DIM);
    ushort* h1b  = zqb + (size_t)chunk * L_DIM;
    ushort* h2b  = h1b + (size_t)chunk * H_DIM;

    cnorm_kernel<<<8, 256, 0, stream>>>(cbs, cnorm);
    prep_wt<<<(L_DIM  * H_DIM + 255) / 256, 256, 0, stream>>>(dec_w1, w1t, L_DIM, H_DIM);
    prep_wt<<<(H_DIM * H_DIM + 255) / 256, 256, 0, stream>>>(dec_w2, w2t, H_DIM, H_DIM);
    prep_wt<<<(H_DIM * D_IN + 255) / 256, 256, 0, stream>>>(dec_w3, w3t, H_DIM, D_IN);

    for (long long ro = 0; ro < N_ROWS; ro += chunk) {
        long long R = N_ROWS - ro;
        if (R > chunk) R = chunk;
        unsigned g1 = (unsigned)(R / 128);
        dim3 g2(g1, 2);
        dim3 g3(g1, 3);
        // encoder (bit-exact fp32)
        gemm_bias<true><<<g1, 256, 0, stream>>>(x + ro * D_IN, enc_w1, enc_b1, bufA, D_IN);
        gemm_bias<true><<<g1, 256, 0, stream>>>(bufA, enc_w2, enc_b2, bufB, H_DIM);
        gemm_z<<<g1, 256, 0, stream>>>(bufB, enc_w3, enc_b3, zbuf);
        // residual VQ (bit-exact; writes bf16 z_q)
        vq10_kernel<<<(unsigned)(R / VQ_RPB), 256, 0, stream>>>(zbuf, cbs, cnorm, zqb,
                                                                idxOut, commitPart, (int)ro);
        // decoder (bf16 MFMA)
        mfma_gemm<true,  true ><<<g2, 256, 0, stream>>>(zqb, w1t, dec_b1, h1b, L_DIM, H_DIM);
        mfma_gemm<true,  true ><<<g2, 256, 0, stream>>>(h1b, w2t, dec_b2, h2b, H_DIM, H_DIM);
        mfma_gemm<false, false><<<g3, 256, 0, stream>>>(h2b, w3t, dec_b3, xrec + ro * D_IN, H_DIM, D_IN);
    }

    commit_finalize<<<1, 256, 0, stream>>>(commitPart, commitOut);
}